// Round 11
// baseline (272.080 us; speedup 1.0000x reference)
//
#include <hip/hip_runtime.h>

#define NBATCH 4
#define NS 2048
#define ND 1024
#define NH 8
#define HD 128
#define NFF 512
#define NE 8
#define NT 65536       /* B*S*H tokens */
#define NBS 8192       /* B*S rows */
#define MU_F 0.7f
#define LN_EPS_F 1e-5f

typedef __attribute__((ext_vector_type(4))) float f32x4;
typedef __attribute__((ext_vector_type(2))) double f64x2;
typedef __attribute__((ext_vector_type(8))) _Float16 f16x8;
typedef __attribute__((ext_vector_type(4))) _Float16 f16x4;
typedef __attribute__((ext_vector_type(2))) _Float16 f16x2;

__device__ __forceinline__ void gload_lds16(const void* g, void* l) {
  __builtin_amdgcn_global_load_lds(
      (const __attribute__((address_space(1))) unsigned int*)g,
      (__attribute__((address_space(3))) unsigned int*)l, 16, 0, 0);
}

// cnt is strided: cnt[e*64] so the 8 counters live in different cache lines/TCC channels
__global__ void zero_cnt_kernel(int* cnt) {
  cnt[threadIdx.x] = 0;
}

// batched transpose + convert: in [batch][R][C] f32 -> out [batch][C][R] f16
// R, C multiples of 32. block (32,8), grid (C/32, R/32, batch)
__global__ void tr_cvt_kernel(const float* __restrict__ in, _Float16* __restrict__ out, int R, int C) {
  __shared__ float tile[32][33];
  int b = blockIdx.z;
  const float* inp = in + (size_t)b * R * C;
  _Float16* outp = out + (size_t)b * R * C;
  int c = blockIdx.x * 32 + threadIdx.x;
  int r0 = blockIdx.y * 32;
  #pragma unroll
  for (int i = 0; i < 4; i++) {
    int r = r0 + threadIdx.y + i * 8;
    tile[threadIdx.y + i * 8][threadIdx.x] = inp[(size_t)r * C + c];
  }
  __syncthreads();
  int rr = r0 + threadIdx.x;
  #pragma unroll
  for (int i = 0; i < 4; i++) {
    int cc = blockIdx.x * 32 + threadIdx.y + i * 8;
    outp[(size_t)cc * R + rr] = (_Float16)tile[threadIdx.x][threadIdx.y + i * 8];
  }
}

// v2: one thread per G[d][o] scalar (65536 threads = 256 blocks, full GPU vs
// v1's 128 half-GPU blocks). Writes directly in Gx2 [kp][o] f64x2 layout.
__global__ void build_G_kernel(const float* __restrict__ split_W, const float* __restrict__ split_b,
                               const float* __restrict__ gate_W, const float* __restrict__ gate_b,
                               double* __restrict__ G, double* __restrict__ gbias) {
  int idx = blockIdx.x * 256 + threadIdx.x;   // = d*64 + o
  int d = idx >> 6, o = idx & 63, h = o >> 3, e = o & 7;
  double acc = 0.0;
  const float* r0 = split_W + (size_t)d * ND + h * 128;
  #pragma unroll 4
  for (int j = 0; j < 128; j++)
    acc += (double)r0[j] * (double)gate_W[j * 8 + e];
  G[((size_t)(d >> 1) * 64 + o) * 2 + (d & 1)] = acc;
  if (idx < 64) {
    double bacc = 0.0;
    for (int j = 0; j < 128; j++)
      bacc += (double)split_b[h * 128 + j] * (double)gate_W[j * 8 + e];
    gbias[idx] = bacc + (double)gate_b[e];
  }
}

// fp64 logits = x @ G + gbias, top-2 per (row,h), softmax, per-expert lists.
// v5: G read directly from global (coalesced, L2-resident); x staged in LDS;
// fused x->fp16; hierarchical atomics.
__global__ __launch_bounds__(256) void gate_kernel(const float* __restrict__ x,
    const f64x2* __restrict__ Gx2, const double* __restrict__ gbias,
    _Float16* __restrict__ x_h,
    float* __restrict__ tkw, int* __restrict__ lists, int* __restrict__ cnt) {
  __shared__ double xsd[16][66];     // 8.25 KB
  __shared__ double lg[16 * 64];     // 8 KB
  __shared__ int lcnt[8];
  __shared__ int lbase[8];
  int tid = threadIdx.x, lane = tid & 63, w = tid >> 6;
  int bs0 = blockIdx.x * 16;
  double acc[4];
  #pragma unroll
  for (int r = 0; r < 4; r++) acc[r] = 0.0;
  int xrow = tid >> 4, xc4 = tid & 15;
  const double* xr = &xsd[0][0] + (w * 4) * 66;
  if (tid < 8) lcnt[tid] = 0;

  for (int ch = 0; ch < 16; ch++) {
    __syncthreads();           // previous chunk's reads complete before overwrite
    float4 xv4 = *(const float4*)(x + (size_t)(bs0 + xrow) * ND + ch * 64 + xc4 * 4);
    f64x2 xa = { (double)xv4.x, (double)xv4.y };
    f64x2 xb = { (double)xv4.z, (double)xv4.w };
    *(f64x2*)&xsd[xrow][xc4 * 4]     = xa;
    *(f64x2*)&xsd[xrow][xc4 * 4 + 2] = xb;
    // fused fp16 conversion of x (replaces cvt kernel)
    f16x4 xh = { (_Float16)xv4.x, (_Float16)xv4.y, (_Float16)xv4.z, (_Float16)xv4.w };
    *(f16x4*)(x_h + (size_t)(bs0 + xrow) * ND + ch * 64 + xc4 * 4) = xh;
    __syncthreads();
    const f64x2* Gc = Gx2 + (size_t)(ch * 32) * 64 + lane;
    #pragma unroll 8
    for (int kp = 0; kp < 32; kp++) {
      f64x2 g = Gc[kp * 64];               // global, coalesced 1KB/wave, L2-hit
      #pragma unroll
      for (int r = 0; r < 4; r++) {
        f64x2 xv = *(const f64x2*)(xr + r * 66 + kp * 2);   // LDS broadcast
        acc[r] += xv.x * g.x;
        acc[r] += xv.y * g.y;
      }
    }
  }
  double gb = gbias[lane];
  #pragma unroll
  for (int r = 0; r < 4; r++)
    lg[(w * 4 + r) * 64 + lane] = acc[r] + gb;
  __syncthreads();

  int i1 = 0, i2 = 0, token = 0, p1 = 0, p2 = 0;
  if (tid < 128) {
    int row = tid >> 3, h = tid & 7;
    const double* L = lg + row * 64 + h * 8;
    double v1 = L[0];
    #pragma unroll
    for (int e2 = 1; e2 < 8; e2++) if (L[e2] > v1) { v1 = L[e2]; i1 = e2; }
    i2 = -1; double v2 = -1e300;
    #pragma unroll
    for (int e2 = 0; e2 < 8; e2++) if (e2 != i1 && L[e2] > v2) { v2 = L[e2]; i2 = e2; }
    float ex = expf((float)(v2 - v1));        // <= 1
    float den = 1.f + ex;
    float g1 = 1.f / den, g2 = ex / den;
    token = (bs0 + row) * 8 + h;
    tkw[token * 2]     = g1;
    tkw[token * 2 + 1] = g2;
    p1 = atomicAdd(&lcnt[i1], 1);             // LDS atomics: cheap
    p2 = atomicAdd(&lcnt[i2], 1);
  }
  __syncthreads();
  if (tid < 8) lbase[tid] = atomicAdd(cnt + tid * 64, lcnt[tid]);   // 8 global atomics/block
  __syncthreads();
  if (tid < 128) {
    lists[(size_t)i1 * NT + lbase[i1] + p1] = token * 2;
    lists[(size_t)i2 * NT + lbase[i2] + p2] = token * 2 + 1;
  }
}

// C[M][N] = A[M][K] @ Bt[N][K]^T + bias; fp16 inputs, fp32 acc.
// 128x128 tile, BK=32, 4 waves (2x2 of 64x64), global_load_lds width 16.
__global__ __launch_bounds__(256) void gemm_f16_kernel(
    const _Float16* __restrict__ A, const _Float16* __restrict__ Bt,
    const float* __restrict__ bias, float* __restrict__ Cf, _Float16* __restrict__ Ch,
    int M, int N, int Kd) {
  __shared__ _Float16 As[128 * 32];
  __shared__ _Float16 Bs[128 * 32];
  int tid = threadIdx.x, lane = tid & 63, w = tid >> 6;
  int wr = w >> 1, wc = w & 1;
  int m0 = blockIdx.y * 128, n0 = blockIdx.x * 128;
  f32x4 acc[4][4];
  #pragma unroll
  for (int i = 0; i < 4; i++)
    #pragma unroll
    for (int j = 0; j < 4; j++) acc[i][j] = (f32x4){0.f, 0.f, 0.f, 0.f};
  int srow = lane >> 2, scol = (lane & 3) * 8;
  int fr = lane & 15, ko = (lane >> 4) * 8;
  const _Float16* Ag = A + (size_t)(m0 + srow) * Kd + scol;
  const _Float16* Bg = Bt + (size_t)(n0 + srow) * Kd + scol;

  for (int k0 = 0; k0 < Kd; k0 += 32) {
    #pragma unroll
    for (int j = 0; j < 2; j++) {
      int rb = (w * 2 + j) * 16;
      gload_lds16(Ag + (size_t)rb * Kd + k0, As + rb * 32);
      gload_lds16(Bg + (size_t)rb * Kd + k0, Bs + rb * 32);
    }
    __syncthreads();
    f16x8 af[4], bq[4];
    #pragma unroll
    for (int mi = 0; mi < 4; mi++) af[mi] = *(const f16x8*)(As + (wr * 64 + mi * 16 + fr) * 32 + ko);
    #pragma unroll
    for (int ni = 0; ni < 4; ni++) bq[ni] = *(const f16x8*)(Bs + (wc * 64 + ni * 16 + fr) * 32 + ko);
    __syncthreads();
    #pragma unroll
    for (int mi = 0; mi < 4; mi++)
      #pragma unroll
      for (int ni = 0; ni < 4; ni++)
        acc[mi][ni] = __builtin_amdgcn_mfma_f32_16x16x32_f16(af[mi], bq[ni], acc[mi][ni], 0, 0, 0);
  }
  int rbase = m0 + wr * 64 + ((lane >> 4) << 2);
  int cbase = n0 + wc * 64 + (lane & 15);
  #pragma unroll
  for (int mi = 0; mi < 4; mi++)
    #pragma unroll
    for (int ni = 0; ni < 4; ni++) {
      int cc = cbase + ni * 16;
      float bv = bias ? bias[cc] : 0.f;
      #pragma unroll
      for (int r = 0; r < 4; r++) {
        int rr = rbase + mi * 16 + r;
        float v = acc[mi][ni][r] + bv;
        if (Cf) Cf[(size_t)rr * N + cc] = v;
        if (Ch) Ch[(size_t)rr * N + cc] = (_Float16)v;
      }
    }
}

// Grouped expert kernel v8: BIG WAVE TILES for LDS-reuse (m93 lever).
// 256 threads, 4 waves (2x2), wave output 64x64 -> each weight/h fragment read
// feeds 4 row-blocks (2x the reuse of v7's 32-row tiles; LDS read traffic per
// block halves). af 64 + acc2 64 + acc1 32 VGPR -> ~190 used; (256,1) = no cap,
// no spill (round-7 lesson: cap = 256/arg2). 3-ring counted-vmcnt staging kept
// (16 phases, vmcnt(4) = leave next stage's 4 loads in flight).
__global__ __launch_bounds__(256, 1) void expert_kernel(
    const _Float16* __restrict__ t_h, const _Float16* __restrict__ W1t, const _Float16* __restrict__ W2t,
    const float* __restrict__ b1, const float* __restrict__ b2,
    const int* __restrict__ cnt, const int* __restrict__ lists, const float* __restrict__ tkw,
    _Float16* __restrict__ slots) {
  int e = blockIdx.x & 7;              // consecutive blocks -> different XCDs
  int m0 = (blockIdx.x >> 3) * 128;
  int count = cnt[e * 64];
  if (m0 >= count) return;
  __shared__ _Float16 ring[3][64 * 128];  // 3 x 16 KB staging ring
  __shared__ _Float16 h_s[128 * 64];      // 16 KB [tok128][ff64] 128B rows
  __shared__ float b1s[NFF];              // 2 KB
  __shared__ float b2s[HD];               // 512 B
  __shared__ int alist[128];
  __shared__ float aw[128];
  int tid = threadIdx.x, lane = tid & 63, w = tid >> 6;   // 4 waves
  int wr = w >> 1, wc = w & 1;         // 2x2 wave grid, wave tile 64x64
  int fr = lane & 15, g = lane >> 4;

  if (tid < 128) {
    int idx = m0 + tid;
    int a = (idx < count) ? lists[(size_t)e * NT + idx] : -1;
    alist[tid] = a;
    aw[tid] = (a >= 0) ? tkw[a] : 0.f;
  }
  b1s[tid] = b1[e * NFF + tid];
  b1s[tid + 256] = b1[e * NFF + tid + 256];
  if (tid < 128) b2s[tid] = b2[e * HD + tid];
  __syncthreads();

  // stage phase p's weights into ring[p%3]. p even: W1 chunk [ff64][d128];
  // p odd: W2 chunk [d128][ff64]. Source pre-swizzled: sg = gg^((r>>1)&7).
  auto stage = [&](int p) {
    if (p >= 16) return;
    int ch = p >> 1;
    _Float16* dst = &ring[p % 3][0];
    if ((p & 1) == 0) {
      #pragma unroll
      for (int j = 0; j < 4; j++) {
        int n = j * 256 + tid;           // 0..1023, 16 granules per 256B row
        int r = n >> 4, gg = n & 15;
        int sg = gg ^ ((r >> 1) & 7);
        gload_lds16(W1t + (size_t)e * (NFF * HD) + (size_t)(ch * 64 + r) * HD + sg * 8, dst + n * 8);
      }
    } else {
      #pragma unroll
      for (int j = 0; j < 4; j++) {
        int n = j * 256 + tid;           // 0..1023, 8 granules per 128B row
        int r = n >> 3, gg = n & 7;
        int sg = gg ^ ((r >> 1) & 7);
        gload_lds16(W2t + (size_t)e * (HD * NFF) + (size_t)r * NFF + ch * 64 + sg * 8, dst + n * 8);
      }
    }
  };

  // gather this wave's 64 token rows into registers (held across all phases)
  f16x8 af[4][4];
  #pragma unroll
  for (int mi = 0; mi < 4; mi++) {
    int rloc = wr * 64 + mi * 16 + fr;
    int a = alist[rloc];
    const _Float16* tb = t_h + (size_t)(a >> 1) * HD;
    #pragma unroll
    for (int ks = 0; ks < 4; ks++) {
      f16x8 v = {0, 0, 0, 0, 0, 0, 0, 0};
      if (a >= 0) v = *(const f16x8*)(tb + ks * 32 + g * 8);
      af[mi][ks] = v;
    }
  }
  asm volatile("s_waitcnt vmcnt(0)" ::: "memory");   // drain gather: loop vmcnt is stage-only
  stage(0); stage(1);
  asm volatile("s_waitcnt vmcnt(4) lgkmcnt(0)\n\ts_barrier" ::: "memory");  // stage(0) landed

  f32x4 acc2[4][4];
  #pragma unroll
  for (int i = 0; i < 4; i++)
    #pragma unroll
    for (int j = 0; j < 4; j++) acc2[i][j] = (f32x4){0.f, 0.f, 0.f, 0.f};

  #pragma unroll
  for (int p = 0; p < 16; p++) {
    stage(p + 2);
    int ch = p >> 1;
    const char* WB = (const char*)&ring[p % 3][0];
    if ((p & 1) == 0) {
      // ---- A: h(:, ch*64..) = relu(t @ W1chunk + b1); wave tile 64 tok x 32 ff ----
      float b1v[2];
      #pragma unroll
      for (int ni = 0; ni < 2; ni++)
        b1v[ni] = b1s[ch * 64 + wc * 32 + ni * 16 + fr];
      f32x4 acc1[4][2];
      #pragma unroll
      for (int i = 0; i < 4; i++)
        #pragma unroll
        for (int j = 0; j < 2; j++) acc1[i][j] = (f32x4){0.f, 0.f, 0.f, 0.f};
      #pragma unroll
      for (int ks = 0; ks < 4; ks++) {
        f16x8 bq[2];
        #pragma unroll
        for (int ni = 0; ni < 2; ni++) {
          int rw = wc * 32 + ni * 16 + fr;       // ff row of chunk (0..63)
          int byte = rw * 256 + ((ks * 64 + g * 16) ^ (((rw >> 1) & 7) << 4));
          bq[ni] = *(const f16x8*)(WB + byte);
        }
        #pragma unroll
        for (int mi = 0; mi < 4; mi++)
          #pragma unroll
          for (int ni = 0; ni < 2; ni++)
            acc1[mi][ni] = __builtin_amdgcn_mfma_f32_16x16x32_f16(af[mi][ks], bq[ni], acc1[mi][ni], 0, 0, 0);
      }
      #pragma unroll
      for (int mi = 0; mi < 4; mi++)
        #pragma unroll
        for (int ni = 0; ni < 2; ni++) {
          int hc = wc * 32 + ni * 16 + fr;
          #pragma unroll
          for (int r = 0; r < 4; r++) {
            int hr = wr * 64 + mi * 16 + g * 4 + r;
            int byte = hr * 128 + ((hc * 2) ^ (((hr >> 1) & 7) << 4));
            *(_Float16*)((char*)h_s + byte) = (_Float16)fmaxf(acc1[mi][ni][r] + b1v[ni], 0.f);
          }
        }
    } else {
      // ---- B: acc2 += h(:, ch) @ W2chunk; wave tile 64 tok x 64 d ----
      #pragma unroll
      for (int ks = 0; ks < 2; ks++) {
        f16x8 ah[4], bq[4];
        #pragma unroll
        for (int mi = 0; mi < 4; mi++) {
          int row = wr * 64 + mi * 16 + fr;
          int byte = row * 128 + ((ks * 64 + g * 16) ^ (((row >> 1) & 7) << 4));
          ah[mi] = *(const f16x8*)((const char*)h_s + byte);
        }
        #pragma unroll
        for (int ni = 0; ni < 4; ni++) {
          int rw = wc * 64 + ni * 16 + fr;       // d row (0..127)
          int byte = rw * 128 + ((ks * 64 + g * 16) ^ (((rw >> 1) & 7) << 4));
          bq[ni] = *(const f16x8*)(WB + byte);
        }
        #pragma unroll
        for (int mi = 0; mi < 4; mi++)
          #pragma unroll
          for (int ni = 0; ni < 4; ni++)
            acc2[mi][ni] = __builtin_amdgcn_mfma_f32_16x16x32_f16(ah[mi], bq[ni], acc2[mi][ni], 0, 0, 0);
      }
    }
    // phase sync: next phase's weights landed (counted), h_s coherent.
    if (p == 14) {
      asm volatile("s_waitcnt vmcnt(0) lgkmcnt(0)\n\ts_barrier" ::: "memory");
    } else if (p < 14) {
      asm volatile("s_waitcnt vmcnt(4) lgkmcnt(0)\n\ts_barrier" ::: "memory");
    }
  }
  // epilogue: gate-scale + fp16 scatter to slots
  #pragma unroll
  for (int mi = 0; mi < 4; mi++)
    #pragma unroll
    for (int ni = 0; ni < 4; ni++) {
      int ncol = wc * 64 + ni * 16 + fr;
      float bv = b2s[ncol];
      #pragma unroll
      for (int r = 0; r < 4; r++) {
        int m = wr * 64 + mi * 16 + g * 4 + r;
        int a = alist[m];
        if (a >= 0)
          slots[(size_t)a * HD + ncol] = (_Float16)(aw[m] * (acc2[mi][ni][r] + bv));
      }
    }
}

// combine slots -> momentum update -> residual -> LayerNorm; writes nm_out (fp32) + out_h (fp16)
// 1 wave per token (2 elems/lane), 4 tokens/block
__global__ __launch_bounds__(256) void combine_ln_kernel(
    const _Float16* __restrict__ slots, const float* __restrict__ momentum,
    const _Float16* __restrict__ t_h, const float* __restrict__ ln_g, const float* __restrict__ ln_b,
    float* __restrict__ nm_out, _Float16* __restrict__ out_h) {
  int w = threadIdx.x >> 6, lane = threadIdx.x & 63;
  int tok = blockIdx.x * 4 + w;
  int d0 = lane * 2;
  f16x2 s0 = *(const f16x2*)(slots + (size_t)tok * 256 + d0);
  f16x2 s1 = *(const f16x2*)(slots + (size_t)tok * 256 + 128 + d0);
  float2 mo = *(const float2*)(momentum + (size_t)tok * HD + d0);
  f16x2 tv = *(const f16x2*)(t_h + (size_t)tok * HD + d0);
  float nm0 = -((float)s0.x + (float)s1.x) + MU_F * mo.x;
  float nm1 = -((float)s0.y + (float)s1.y) + MU_F * mo.y;
  float2 nm2; nm2.x = nm0; nm2.y = nm1;
  *(float2*)(nm_out + (size_t)tok * HD + d0) = nm2;
  float r0 = (float)tv.x + nm0;
  float r1 = (float)tv.y + nm1;
  float s = r0 + r1, sq = r0 * r0 + r1 * r1;
  #pragma unroll
  for (int m = 1; m < 64; m <<= 1) { s += __shfl_xor(s, m, 64); sq += __shfl_xor(sq, m, 64); }
  float mean = s * (1.f / 128.f);
  float var = sq * (1.f / 128.f) - mean * mean;
  float is = rsqrtf(var + LN_EPS_F);
  float y0 = (r0 - mean) * is * ln_g[d0] + ln_b[d0];
  float y1 = (r1 - mean) * is * ln_g[d0 + 1] + ln_b[d0 + 1];
  f16x2 yo = { (_Float16)y0, (_Float16)y1 };
  *(f16x2*)(out_h + (size_t)tok * HD + d0) = yo;
}

extern "C" void kernel_launch(void* const* d_in, const int* in_sizes, int n_in,
                              void* d_out, int out_size, void* d_ws, size_t ws_size,
                              hipStream_t stream) {
  const float* x        = (const float*)d_in[0];
  const float* momentum = (const float*)d_in[1];
  const float* split_W  = (const float*)d_in[2];
  const float* split_b  = (const float*)d_in[3];
  const float* gate_W   = (const float*)d_in[4];
  const float* gate_b   = (const float*)d_in[5];
  const float* W1       = (const float*)d_in[6];
  const float* b1       = (const float*)d_in[7];
  const float* W2       = (const float*)d_in[8];
  const float* b2       = (const float*)d_in[9];
  const float* ln_g     = (const float*)d_in[10];
  const float* ln_b     = (const float*)d_in[11];
  const float* merge_W  = (const float*)d_in[12];
  const float* merge_b  = (const float*)d_in[13];
  float* final_out = (float*)d_out;
  float* nm_out    = final_out + (size_t)NBS * ND;

  char* ws = (char*)d_ws;
  size_t off = 0;
  auto alloc = [&](size_t bytes) { void* p = ws + off; off = (off + bytes + 255) & ~(size_t)255; return p; };
  _Float16* x_h   = (_Float16*)alloc((size_t)NBS * ND * 2);
  _Float16* t_h   = (_Float16*)alloc((size_t)NT * HD * 2);
  _Float16* out_h = (_Float16*)alloc((size_t)NT * HD * 2);
  _Float16* sWt   = (_Float16*)alloc((size_t)ND * ND * 2);
  _Float16* mWt   = (_Float16*)alloc((size_t)ND * ND * 2);
  _Float16* W1t   = (_Float16*)alloc((size_t)NE * HD * NFF * 2);
  _Float16* W2t   = (_Float16*)alloc((size_t)NE * HD * NFF * 2);
  f64x2*    Gx2   = (f64x2*)alloc((size_t)512 * 64 * 16);
  double*   gbias = (double*)alloc(64 * 8);
  float*    tkw   = (float*)alloc((size_t)NT * 2 * 4);
  int*      lists = (int*)alloc((size_t)NE * NT * 4);
  int*      cnt   = (int*)alloc(512 * 4);
  _Float16* slots = (_Float16*)alloc((size_t)NT * 2 * HD * 2);
  (void)in_sizes; (void)n_in; (void)out_size; (void)ws_size;

  zero_cnt_kernel<<<1, 512, 0, stream>>>(cnt);
  tr_cvt_kernel<<<dim3(32, 32, 1), dim3(32, 8), 0, stream>>>(split_W, sWt, ND, ND);
  tr_cvt_kernel<<<dim3(32, 32, 1), dim3(32, 8), 0, stream>>>(merge_W, mWt, ND, ND);
  tr_cvt_kernel<<<dim3(16, 4, 8), dim3(32, 8), 0, stream>>>(W1, W1t, HD, NFF);
  tr_cvt_kernel<<<dim3(4, 16, 8), dim3(32, 8), 0, stream>>>(W2, W2t, NFF, HD);
  build_G_kernel<<<256, 256, 0, stream>>>(split_W, split_b, gate_W, gate_b, (double*)Gx2, gbias);
  // gate also produces x_h (fused convert), so it runs before the split GEMM
  gate_kernel<<<512, 256, 0, stream>>>(x, Gx2, gbias, x_h, tkw, lists, cnt);
  // t = x @ split_W + split_b   (fp16 out for downstream MFMA)
  gemm_f16_kernel<<<dim3(8, 64), 256, 0, stream>>>(x_h, sWt, split_b, nullptr, t_h, NBS, ND, ND);
  expert_kernel<<<NE * 512, 256, 0, stream>>>(t_h, W1t, W2t, b1, b2, cnt, lists, tkw, slots);
  combine_ln_kernel<<<NT / 4, 256, 0, stream>>>(slots, momentum, t_h, ln_g, ln_b, nm_out, out_h);
  // final = out @ merge_W + merge_b
  gemm_f16_kernel<<<dim3(8, 64), 256, 0, stream>>>(out_h, mWt, merge_b, final_out, nullptr, NBS, ND, ND);
}

// Round 12
// 243.915 us; speedup vs baseline: 1.1155x; 1.1155x over previous
//
#include <hip/hip_runtime.h>

#define NBATCH 4
#define NS 2048
#define ND 1024
#define NH 8
#define HD 128
#define NFF 512
#define NE 8
#define NT 65536       /* B*S*H tokens */
#define NBS 8192       /* B*S rows */
#define MU_F 0.7f
#define LN_EPS_F 1e-5f

typedef __attribute__((ext_vector_type(4))) float f32x4;
typedef __attribute__((ext_vector_type(2))) double f64x2;
typedef __attribute__((ext_vector_type(8))) _Float16 f16x8;
typedef __attribute__((ext_vector_type(4))) _Float16 f16x4;
typedef __attribute__((ext_vector_type(2))) _Float16 f16x2;

__device__ __forceinline__ void gload_lds16(const void* g, void* l) {
  __builtin_amdgcn_global_load_lds(
      (const __attribute__((address_space(1))) unsigned int*)g,
      (__attribute__((address_space(3))) unsigned int*)l, 16, 0, 0);
}

// cnt is strided: cnt[e*64] so the 8 counters live in different cache lines/TCC channels
__global__ void zero_cnt_kernel(int* cnt) {
  cnt[threadIdx.x] = 0;
}

// batched transpose + convert: in [batch][R][C] f32 -> out [batch][C][R] f16
// R, C multiples of 32. block (32,8), grid (C/32, R/32, batch)
__global__ void tr_cvt_kernel(const float* __restrict__ in, _Float16* __restrict__ out, int R, int C) {
  __shared__ float tile[32][33];
  int b = blockIdx.z;
  const float* inp = in + (size_t)b * R * C;
  _Float16* outp = out + (size_t)b * R * C;
  int c = blockIdx.x * 32 + threadIdx.x;
  int r0 = blockIdx.y * 32;
  #pragma unroll
  for (int i = 0; i < 4; i++) {
    int r = r0 + threadIdx.y + i * 8;
    tile[threadIdx.y + i * 8][threadIdx.x] = inp[(size_t)r * C + c];
  }
  __syncthreads();
  int rr = r0 + threadIdx.x;
  #pragma unroll
  for (int i = 0; i < 4; i++) {
    int cc = blockIdx.x * 32 + threadIdx.y + i * 8;
    outp[(size_t)cc * R + rr] = (_Float16)tile[threadIdx.x][threadIdx.y + i * 8];
  }
}

// v2: one thread per G[d][o] scalar (65536 threads = 256 blocks, full GPU).
// Writes directly in Gx2 [kp][o] f64x2 layout.
__global__ void build_G_kernel(const float* __restrict__ split_W, const float* __restrict__ split_b,
                               const float* __restrict__ gate_W, const float* __restrict__ gate_b,
                               double* __restrict__ G, double* __restrict__ gbias) {
  int idx = blockIdx.x * 256 + threadIdx.x;   // = d*64 + o
  int d = idx >> 6, o = idx & 63, h = o >> 3, e = o & 7;
  double acc = 0.0;
  const float* r0 = split_W + (size_t)d * ND + h * 128;
  #pragma unroll 4
  for (int j = 0; j < 128; j++)
    acc += (double)r0[j] * (double)gate_W[j * 8 + e];
  G[((size_t)(d >> 1) * 64 + o) * 2 + (d & 1)] = acc;
  if (idx < 64) {
    double bacc = 0.0;
    for (int j = 0; j < 128; j++)
      bacc += (double)split_b[h * 128 + j] * (double)gate_W[j * 8 + e];
    gbias[idx] = bacc + (double)gate_b[e];
  }
}

// fp64 logits = x @ G + gbias, top-2 per (row,h), softmax, per-expert lists.
// v5: G read directly from global (coalesced, L2-resident); x staged in LDS;
// fused x->fp16; hierarchical atomics.
__global__ __launch_bounds__(256) void gate_kernel(const float* __restrict__ x,
    const f64x2* __restrict__ Gx2, const double* __restrict__ gbias,
    _Float16* __restrict__ x_h,
    float* __restrict__ tkw, int* __restrict__ lists, int* __restrict__ cnt) {
  __shared__ double xsd[16][66];     // 8.25 KB
  __shared__ double lg[16 * 64];     // 8 KB
  __shared__ int lcnt[8];
  __shared__ int lbase[8];
  int tid = threadIdx.x, lane = tid & 63, w = tid >> 6;
  int bs0 = blockIdx.x * 16;
  double acc[4];
  #pragma unroll
  for (int r = 0; r < 4; r++) acc[r] = 0.0;
  int xrow = tid >> 4, xc4 = tid & 15;
  const double* xr = &xsd[0][0] + (w * 4) * 66;
  if (tid < 8) lcnt[tid] = 0;

  for (int ch = 0; ch < 16; ch++) {
    __syncthreads();           // previous chunk's reads complete before overwrite
    float4 xv4 = *(const float4*)(x + (size_t)(bs0 + xrow) * ND + ch * 64 + xc4 * 4);
    f64x2 xa = { (double)xv4.x, (double)xv4.y };
    f64x2 xb = { (double)xv4.z, (double)xv4.w };
    *(f64x2*)&xsd[xrow][xc4 * 4]     = xa;
    *(f64x2*)&xsd[xrow][xc4 * 4 + 2] = xb;
    // fused fp16 conversion of x (replaces cvt kernel)
    f16x4 xh = { (_Float16)xv4.x, (_Float16)xv4.y, (_Float16)xv4.z, (_Float16)xv4.w };
    *(f16x4*)(x_h + (size_t)(bs0 + xrow) * ND + ch * 64 + xc4 * 4) = xh;
    __syncthreads();
    const f64x2* Gc = Gx2 + (size_t)(ch * 32) * 64 + lane;
    #pragma unroll 8
    for (int kp = 0; kp < 32; kp++) {
      f64x2 g = Gc[kp * 64];               // global, coalesced 1KB/wave, L2-hit
      #pragma unroll
      for (int r = 0; r < 4; r++) {
        f64x2 xv = *(const f64x2*)(xr + r * 66 + kp * 2);   // LDS broadcast
        acc[r] += xv.x * g.x;
        acc[r] += xv.y * g.y;
      }
    }
  }
  double gb = gbias[lane];
  #pragma unroll
  for (int r = 0; r < 4; r++)
    lg[(w * 4 + r) * 64 + lane] = acc[r] + gb;
  __syncthreads();

  int i1 = 0, i2 = 0, token = 0, p1 = 0, p2 = 0;
  if (tid < 128) {
    int row = tid >> 3, h = tid & 7;
    const double* L = lg + row * 64 + h * 8;
    double v1 = L[0];
    #pragma unroll
    for (int e2 = 1; e2 < 8; e2++) if (L[e2] > v1) { v1 = L[e2]; i1 = e2; }
    i2 = -1; double v2 = -1e300;
    #pragma unroll
    for (int e2 = 0; e2 < 8; e2++) if (e2 != i1 && L[e2] > v2) { v2 = L[e2]; i2 = e2; }
    float ex = expf((float)(v2 - v1));        // <= 1
    float den = 1.f + ex;
    float g1 = 1.f / den, g2 = ex / den;
    token = (bs0 + row) * 8 + h;
    tkw[token * 2]     = g1;
    tkw[token * 2 + 1] = g2;
    p1 = atomicAdd(&lcnt[i1], 1);             // LDS atomics: cheap
    p2 = atomicAdd(&lcnt[i2], 1);
  }
  __syncthreads();
  if (tid < 8) lbase[tid] = atomicAdd(cnt + tid * 64, lcnt[tid]);   // 8 global atomics/block
  __syncthreads();
  if (tid < 128) {
    lists[(size_t)i1 * NT + lbase[i1] + p1] = token * 2;
    lists[(size_t)i2 * NT + lbase[i2] + p2] = token * 2 + 1;
  }
}

// C[M][N] = A[M][K] @ Bt[N][K]^T + bias; fp16 inputs, fp32 acc.
// 128x128 tile, BK=32, 4 waves (2x2 of 64x64), global_load_lds width 16.
__global__ __launch_bounds__(256) void gemm_f16_kernel(
    const _Float16* __restrict__ A, const _Float16* __restrict__ Bt,
    const float* __restrict__ bias, float* __restrict__ Cf, _Float16* __restrict__ Ch,
    int M, int N, int Kd) {
  __shared__ _Float16 As[128 * 32];
  __shared__ _Float16 Bs[128 * 32];
  int tid = threadIdx.x, lane = tid & 63, w = tid >> 6;
  int wr = w >> 1, wc = w & 1;
  int m0 = blockIdx.y * 128, n0 = blockIdx.x * 128;
  f32x4 acc[4][4];
  #pragma unroll
  for (int i = 0; i < 4; i++)
    #pragma unroll
    for (int j = 0; j < 4; j++) acc[i][j] = (f32x4){0.f, 0.f, 0.f, 0.f};
  int srow = lane >> 2, scol = (lane & 3) * 8;
  int fr = lane & 15, ko = (lane >> 4) * 8;
  const _Float16* Ag = A + (size_t)(m0 + srow) * Kd + scol;
  const _Float16* Bg = Bt + (size_t)(n0 + srow) * Kd + scol;

  for (int k0 = 0; k0 < Kd; k0 += 32) {
    #pragma unroll
    for (int j = 0; j < 2; j++) {
      int rb = (w * 2 + j) * 16;
      gload_lds16(Ag + (size_t)rb * Kd + k0, As + rb * 32);
      gload_lds16(Bg + (size_t)rb * Kd + k0, Bs + rb * 32);
    }
    __syncthreads();
    f16x8 af[4], bq[4];
    #pragma unroll
    for (int mi = 0; mi < 4; mi++) af[mi] = *(const f16x8*)(As + (wr * 64 + mi * 16 + fr) * 32 + ko);
    #pragma unroll
    for (int ni = 0; ni < 4; ni++) bq[ni] = *(const f16x8*)(Bs + (wc * 64 + ni * 16 + fr) * 32 + ko);
    __syncthreads();
    #pragma unroll
    for (int mi = 0; mi < 4; mi++)
      #pragma unroll
      for (int ni = 0; ni < 4; ni++)
        acc[mi][ni] = __builtin_amdgcn_mfma_f32_16x16x32_f16(af[mi], bq[ni], acc[mi][ni], 0, 0, 0);
  }
  int rbase = m0 + wr * 64 + ((lane >> 4) << 2);
  int cbase = n0 + wc * 64 + (lane & 15);
  #pragma unroll
  for (int mi = 0; mi < 4; mi++)
    #pragma unroll
    for (int ni = 0; ni < 4; ni++) {
      int cc = cbase + ni * 16;
      float bv = bias ? bias[cc] : 0.f;
      #pragma unroll
      for (int r = 0; r < 4; r++) {
        int rr = rbase + mi * 16 + r;
        float v = acc[mi][ni][r] + bv;
        if (Cf) Cf[(size_t)rr * N + cc] = v;
        if (Ch) Ch[(size_t)rr * N + cc] = (_Float16)v;
      }
    }
}

// Grouped expert kernel v9 = v7 + SWAPPED-OPERAND PHASE A.
// acc1 = mfma(bq, af) computes h^T: each reg-quad = 4 consecutive ff for one
// token (col=lane&15=tok, row=g*4+r=ff). Pack 4 -> f16x4 -> ONE b64 write into
// the same [tok][ff] h_s layout phase B already b128-reads. h writes drop
// 16 scalar -> 4 b64 per thread per chunk (1024 -> 256 wave-writes/block).
// Bias is now ff-per-reg: 8 scalar LDS reads/chunk from b1s. Phase B, ring,
// counted-vmcnt sync: byte-for-byte v7 (best known: 76us, total 247.8).
__global__ __launch_bounds__(512, 2) void expert_kernel(
    const _Float16* __restrict__ t_h, const _Float16* __restrict__ W1t, const _Float16* __restrict__ W2t,
    const float* __restrict__ b1, const float* __restrict__ b2,
    const int* __restrict__ cnt, const int* __restrict__ lists, const float* __restrict__ tkw,
    _Float16* __restrict__ slots) {
  int e = blockIdx.x & 7;              // consecutive blocks -> different XCDs
  int m0 = (blockIdx.x >> 3) * 128;
  int count = cnt[e * 64];
  if (m0 >= count) return;
  __shared__ _Float16 ring[3][64 * 128];  // 3 x 16 KB staging ring
  __shared__ _Float16 h_s[128 * 64];      // 16 KB [tok128][ff64] 128B rows
  __shared__ float b1s[NFF];              // 2 KB
  __shared__ float b2s[HD];               // 512 B
  __shared__ int alist[128];
  __shared__ float aw[128];
  int tid = threadIdx.x, lane = tid & 63, w = tid >> 6;
  int wr = w >> 1, wc = w & 1;         // 4 row-quarters (32) x 2 col-halves (64)
  int fr = lane & 15, g = lane >> 4;

  if (tid < 128) {
    int idx = m0 + tid;
    int a = (idx < count) ? lists[(size_t)e * NT + idx] : -1;
    alist[tid] = a;
    aw[tid] = (a >= 0) ? tkw[a] : 0.f;
  }
  b1s[tid] = b1[e * NFF + tid];
  if (tid < 128) b2s[tid] = b2[e * HD + tid];
  __syncthreads();

  // stage phase p's weights into ring[p%3]. p even: W1 chunk [ff64][d128];
  // p odd: W2 chunk [d128][ff64]. Source pre-swizzled: sg = gg^((r>>1)&7).
  auto stage = [&](int p) {
    if (p >= 16) return;
    int ch = p >> 1;
    _Float16* dst = &ring[p % 3][0];
    if ((p & 1) == 0) {
      #pragma unroll
      for (int j = 0; j < 2; j++) {
        int n = j * 512 + tid;           // 16 granules per 256B row
        int r = n >> 4, gg = n & 15;
        int sg = gg ^ ((r >> 1) & 7);
        gload_lds16(W1t + (size_t)e * (NFF * HD) + (size_t)(ch * 64 + r) * HD + sg * 8, dst + n * 8);
      }
    } else {
      #pragma unroll
      for (int j = 0; j < 2; j++) {
        int n = j * 512 + tid;           // 8 granules per 128B row
        int r = n >> 3, gg = n & 7;
        int sg = gg ^ ((r >> 1) & 7);
        gload_lds16(W2t + (size_t)e * (HD * NFF) + (size_t)r * NFF + ch * 64 + sg * 8, dst + n * 8);
      }
    }
  };

  // gather this wave's 32 token rows into registers (held across all phases)
  f16x8 af[2][4];
  #pragma unroll
  for (int mi = 0; mi < 2; mi++) {
    int rloc = wr * 32 + mi * 16 + fr;
    int a = alist[rloc];
    const _Float16* tb = t_h + (size_t)(a >> 1) * HD;
    #pragma unroll
    for (int ks = 0; ks < 4; ks++) {
      f16x8 v = {0, 0, 0, 0, 0, 0, 0, 0};
      if (a >= 0) v = *(const f16x8*)(tb + ks * 32 + g * 8);
      af[mi][ks] = v;
    }
  }
  asm volatile("s_waitcnt vmcnt(0)" ::: "memory");   // drain gather: loop vmcnt is stage-only
  stage(0); stage(1);
  asm volatile("s_waitcnt vmcnt(2) lgkmcnt(0)\n\ts_barrier" ::: "memory");  // stage(0) landed

  f32x4 acc2[2][4];
  #pragma unroll
  for (int i = 0; i < 2; i++)
    #pragma unroll
    for (int j = 0; j < 4; j++) acc2[i][j] = (f32x4){0.f, 0.f, 0.f, 0.f};

  #pragma unroll
  for (int p = 0; p < 16; p++) {
    stage(p + 2);
    int ch = p >> 1;
    const char* WB = (const char*)&ring[p % 3][0];
    if ((p & 1) == 0) {
      // ---- A (swapped): acc1 = W1^T . t^T = h^T; reg-quad = 4 consecutive ff ----
      float b1r[2][4];
      #pragma unroll
      for (int ni = 0; ni < 2; ni++)
        #pragma unroll
        for (int r = 0; r < 4; r++)
          b1r[ni][r] = b1s[ch * 64 + wc * 32 + ni * 16 + g * 4 + r];
      f32x4 acc1[2][2];    // [mi tok-block][ni ff-block]
      #pragma unroll
      for (int i = 0; i < 2; i++)
        #pragma unroll
        for (int j = 0; j < 2; j++) acc1[i][j] = (f32x4){0.f, 0.f, 0.f, 0.f};
      #pragma unroll
      for (int ks = 0; ks < 4; ks++) {
        f16x8 bq[2];
        #pragma unroll
        for (int ni = 0; ni < 2; ni++) {
          int rw = wc * 32 + ni * 16 + fr;       // ff row of chunk (0..63)
          int byte = rw * 256 + ((ks * 64 + g * 16) ^ (((rw >> 1) & 7) << 4));
          bq[ni] = *(const f16x8*)(WB + byte);
        }
        #pragma unroll
        for (int mi = 0; mi < 2; mi++)
          #pragma unroll
          for (int ni = 0; ni < 2; ni++)
            acc1[mi][ni] = __builtin_amdgcn_mfma_f32_16x16x32_f16(bq[ni], af[mi][ks], acc1[mi][ni], 0, 0, 0);
      }
      // relu + bias -> pack 4 consecutive ff -> single b64 write per (mi,ni)
      #pragma unroll
      for (int mi = 0; mi < 2; mi++)
        #pragma unroll
        for (int ni = 0; ni < 2; ni++) {
          f16x4 hv;
          #pragma unroll
          for (int r = 0; r < 4; r++)
            hv[r] = (_Float16)fmaxf(acc1[mi][ni][r] + b1r[ni][r], 0.f);
          int tok = wr * 32 + mi * 16 + fr;
          int foff = wc * 64 + ni * 32 + g * 8;       // ff*2 bytes
          int byte = tok * 128 + (foff ^ (((tok >> 1) & 7) << 4));
          *(f16x4*)((char*)h_s + byte) = hv;
        }
    } else {
      // ---- B: acc2 += h(:, ch) @ W2chunk (unchanged from v7) ----
      #pragma unroll
      for (int ks = 0; ks < 2; ks++) {
        f16x8 ah[2], bq[4];
        #pragma unroll
        for (int mi = 0; mi < 2; mi++) {
          int row = wr * 32 + mi * 16 + fr;
          int byte = row * 128 + ((ks * 64 + g * 16) ^ (((row >> 1) & 7) << 4));
          ah[mi] = *(const f16x8*)((const char*)h_s + byte);
        }
        #pragma unroll
        for (int ni = 0; ni < 4; ni++) {
          int rw = wc * 64 + ni * 16 + fr;       // d row (0..127)
          int byte = rw * 128 + ((ks * 64 + g * 16) ^ (((rw >> 1) & 7) << 4));
          bq[ni] = *(const f16x8*)((const char*)&ring[p % 3][0] + byte);
        }
        #pragma unroll
        for (int mi = 0; mi < 2; mi++)
          #pragma unroll
          for (int ni = 0; ni < 4; ni++)
            acc2[mi][ni] = __builtin_amdgcn_mfma_f32_16x16x32_f16(ah[mi], bq[ni], acc2[mi][ni], 0, 0, 0);
      }
    }
    // phase sync: next phase's weights landed (counted), h_s coherent.
    if (p == 14) {
      asm volatile("s_waitcnt vmcnt(0) lgkmcnt(0)\n\ts_barrier" ::: "memory");
    } else if (p < 14) {
      asm volatile("s_waitcnt vmcnt(2) lgkmcnt(0)\n\ts_barrier" ::: "memory");
    }
  }
  // epilogue: gate-scale + fp16 scatter to slots
  #pragma unroll
  for (int mi = 0; mi < 2; mi++)
    #pragma unroll
    for (int ni = 0; ni < 4; ni++) {
      int ncol = wc * 64 + ni * 16 + fr;
      float bv = b2s[ncol];
      #pragma unroll
      for (int r = 0; r < 4; r++) {
        int m = wr * 32 + mi * 16 + g * 4 + r;
        int a = alist[m];
        if (a >= 0)
          slots[(size_t)a * HD + ncol] = (_Float16)(aw[m] * (acc2[mi][ni][r] + bv));
      }
    }
}

// combine slots -> momentum update -> residual -> LayerNorm; writes nm_out (fp32) + out_h (fp16)
// 1 wave per token (2 elems/lane), 4 tokens/block
__global__ __launch_bounds__(256) void combine_ln_kernel(
    const _Float16* __restrict__ slots, const float* __restrict__ momentum,
    const _Float16* __restrict__ t_h, const float* __restrict__ ln_g, const float* __restrict__ ln_b,
    float* __restrict__ nm_out, _Float16* __restrict__ out_h) {
  int w = threadIdx.x >> 6, lane = threadIdx.x & 63;
  int tok = blockIdx.x * 4 + w;
  int d0 = lane * 2;
  f16x2 s0 = *(const f16x2*)(slots + (size_t)tok * 256 + d0);
  f16x2 s1 = *(const f16x2*)(slots + (size_t)tok * 256 + 128 + d0);
  float2 mo = *(const float2*)(momentum + (size_t)tok * HD + d0);
  f16x2 tv = *(const f16x2*)(t_h + (size_t)tok * HD + d0);
  float nm0 = -((float)s0.x + (float)s1.x) + MU_F * mo.x;
  float nm1 = -((float)s0.y + (float)s1.y) + MU_F * mo.y;
  float2 nm2; nm2.x = nm0; nm2.y = nm1;
  *(float2*)(nm_out + (size_t)tok * HD + d0) = nm2;
  float r0 = (float)tv.x + nm0;
  float r1 = (float)tv.y + nm1;
  float s = r0 + r1, sq = r0 * r0 + r1 * r1;
  #pragma unroll
  for (int m = 1; m < 64; m <<= 1) { s += __shfl_xor(s, m, 64); sq += __shfl_xor(sq, m, 64); }
  float mean = s * (1.f / 128.f);
  float var = sq * (1.f / 128.f) - mean * mean;
  float is = rsqrtf(var + LN_EPS_F);
  float y0 = (r0 - mean) * is * ln_g[d0] + ln_b[d0];
  float y1 = (r1 - mean) * is * ln_g[d0 + 1] + ln_b[d0 + 1];
  f16x2 yo = { (_Float16)y0, (_Float16)y1 };
  *(f16x2*)(out_h + (size_t)tok * HD + d0) = yo;
}

extern "C" void kernel_launch(void* const* d_in, const int* in_sizes, int n_in,
                              void* d_out, int out_size, void* d_ws, size_t ws_size,
                              hipStream_t stream) {
  const float* x        = (const float*)d_in[0];
  const float* momentum = (const float*)d_in[1];
  const float* split_W  = (const float*)d_in[2];
  const float* split_b  = (const float*)d_in[3];
  const float* gate_W   = (const float*)d_in[4];
  const float* gate_b   = (const float*)d_in[5];
  const float* W1       = (const float*)d_in[6];
  const float* b1       = (const float*)d_in[7];
  const float* W2       = (const float*)d_in[8];
  const float* b2       = (const float*)d_in[9];
  const float* ln_g     = (const float*)d_in[10];
  const float* ln_b     = (const float*)d_in[11];
  const float* merge_W  = (const float*)d_in[12];
  const float* merge_b  = (const float*)d_in[13];
  float* final_out = (float*)d_out;
  float* nm_out    = final_out + (size_t)NBS * ND;

  char* ws = (char*)d_ws;
  size_t off = 0;
  auto alloc = [&](size_t bytes) { void* p = ws + off; off = (off + bytes + 255) & ~(size_t)255; return p; };
  _Float16* x_h   = (_Float16*)alloc((size_t)NBS * ND * 2);
  _Float16* t_h   = (_Float16*)alloc((size_t)NT * HD * 2);
  _Float16* out_h = (_Float16*)alloc((size_t)NT * HD * 2);
  _Float16* sWt   = (_Float16*)alloc((size_t)ND * ND * 2);
  _Float16* mWt   = (_Float16*)alloc((size_t)ND * ND * 2);
  _Float16* W1t   = (_Float16*)alloc((size_t)NE * HD * NFF * 2);
  _Float16* W2t   = (_Float16*)alloc((size_t)NE * HD * NFF * 2);
  f64x2*    Gx2   = (f64x2*)alloc((size_t)512 * 64 * 16);
  double*   gbias = (double*)alloc(64 * 8);
  float*    tkw   = (float*)alloc((size_t)NT * 2 * 4);
  int*      lists = (int*)alloc((size_t)NE * NT * 4);
  int*      cnt   = (int*)alloc(512 * 4);
  _Float16* slots = (_Float16*)alloc((size_t)NT * 2 * HD * 2);
  (void)in_sizes; (void)n_in; (void)out_size; (void)ws_size;

  zero_cnt_kernel<<<1, 512, 0, stream>>>(cnt);
  tr_cvt_kernel<<<dim3(32, 32, 1), dim3(32, 8), 0, stream>>>(split_W, sWt, ND, ND);
  tr_cvt_kernel<<<dim3(32, 32, 1), dim3(32, 8), 0, stream>>>(merge_W, mWt, ND, ND);
  tr_cvt_kernel<<<dim3(16, 4, 8), dim3(32, 8), 0, stream>>>(W1, W1t, HD, NFF);
  tr_cvt_kernel<<<dim3(4, 16, 8), dim3(32, 8), 0, stream>>>(W2, W2t, NFF, HD);
  build_G_kernel<<<256, 256, 0, stream>>>(split_W, split_b, gate_W, gate_b, (double*)Gx2, gbias);
  // gate also produces x_h (fused convert), so it runs before the split GEMM
  gate_kernel<<<512, 256, 0, stream>>>(x, Gx2, gbias, x_h, tkw, lists, cnt);
  // t = x @ split_W + split_b   (fp16 out for downstream MFMA)
  gemm_f16_kernel<<<dim3(8, 64), 256, 0, stream>>>(x_h, sWt, split_b, nullptr, t_h, NBS, ND, ND);
  expert_kernel<<<NE * 512, 512, 0, stream>>>(t_h, W1t, W2t, b1, b2, cnt, lists, tkw, slots);
  combine_ln_kernel<<<NT / 4, 256, 0, stream>>>(slots, momentum, t_h, ln_g, ln_b, nm_out, out_h);
  // final = out @ merge_W + merge_b
  gemm_f16_kernel<<<dim3(8, 64), 256, 0, stream>>>(out_h, mWt, merge_b, final_out, nullptr, NBS, ND, ND);
}

// Round 13
// 240.246 us; speedup vs baseline: 1.1325x; 1.0153x over previous
//
#include <hip/hip_runtime.h>

#define NBATCH 4
#define NS 2048
#define ND 1024
#define NH 8
#define HD 128
#define NFF 512
#define NE 8
#define NT 65536       /* B*S*H tokens */
#define NBS 8192       /* B*S rows */
#define MU_F 0.7f
#define LN_EPS_F 1e-5f

typedef __attribute__((ext_vector_type(4))) float f32x4;
typedef __attribute__((ext_vector_type(2))) double f64x2;
typedef __attribute__((ext_vector_type(8))) _Float16 f16x8;
typedef __attribute__((ext_vector_type(4))) _Float16 f16x4;
typedef __attribute__((ext_vector_type(2))) _Float16 f16x2;

__device__ __forceinline__ void gload_lds16(const void* g, void* l) {
  __builtin_amdgcn_global_load_lds(
      (const __attribute__((address_space(1))) unsigned int*)g,
      (__attribute__((address_space(3))) unsigned int*)l, 16, 0, 0);
}

// cnt is strided: cnt[e*64] so the 8 counters live in different cache lines/TCC channels
__global__ void zero_cnt_kernel(int* cnt) {
  cnt[threadIdx.x] = 0;
}

// batched transpose + convert: in [batch][R][C] f32 -> out [batch][C][R] f16
// R, C multiples of 32. block (32,8), grid (C/32, R/32, batch)
__global__ void tr_cvt_kernel(const float* __restrict__ in, _Float16* __restrict__ out, int R, int C) {
  __shared__ float tile[32][33];
  int b = blockIdx.z;
  const float* inp = in + (size_t)b * R * C;
  _Float16* outp = out + (size_t)b * R * C;
  int c = blockIdx.x * 32 + threadIdx.x;
  int r0 = blockIdx.y * 32;
  #pragma unroll
  for (int i = 0; i < 4; i++) {
    int r = r0 + threadIdx.y + i * 8;
    tile[threadIdx.y + i * 8][threadIdx.x] = inp[(size_t)r * C + c];
  }
  __syncthreads();
  int rr = r0 + threadIdx.x;
  #pragma unroll
  for (int i = 0; i < 4; i++) {
    int cc = blockIdx.x * 32 + threadIdx.y + i * 8;
    outp[(size_t)cc * R + rr] = (_Float16)tile[threadIdx.x][threadIdx.y + i * 8];
  }
}

// v2: one thread per G[d][o] scalar (65536 threads = 256 blocks, full GPU).
// Writes directly in Gx2 [kp][o] f64x2 layout.
__global__ void build_G_kernel(const float* __restrict__ split_W, const float* __restrict__ split_b,
                               const float* __restrict__ gate_W, const float* __restrict__ gate_b,
                               double* __restrict__ G, double* __restrict__ gbias) {
  int idx = blockIdx.x * 256 + threadIdx.x;   // = d*64 + o
  int d = idx >> 6, o = idx & 63, h = o >> 3, e = o & 7;
  double acc = 0.0;
  const float* r0 = split_W + (size_t)d * ND + h * 128;
  #pragma unroll 4
  for (int j = 0; j < 128; j++)
    acc += (double)r0[j] * (double)gate_W[j * 8 + e];
  G[((size_t)(d >> 1) * 64 + o) * 2 + (d & 1)] = acc;
  if (idx < 64) {
    double bacc = 0.0;
    for (int j = 0; j < 128; j++)
      bacc += (double)split_b[h * 128 + j] * (double)gate_W[j * 8 + e];
    gbias[idx] = bacc + (double)gate_b[e];
  }
}

// fp64 logits = x @ G + gbias, top-2 per (row,h), softmax, per-expert lists.
// v6: G chunk async-staged to LDS via global_load_lds (zero VGPR cost -- v5's
// VGPR-path global reads were MLP-starved at VGPR=40, 74us latency-bound).
// Gx2 global layout == LDS layout, so staging is a linear 32KB copy; compute
// read Gs[kp*64+lane] is 16B/lane contiguous = conflict-free (v4-verified).
// LDS 49.5KB -> co-resident blocks cover the per-chunk drain. Fused x_h +
// hierarchical atomics kept.
__global__ __launch_bounds__(256) void gate_kernel(const float* __restrict__ x,
    const f64x2* __restrict__ Gx2, const double* __restrict__ gbias,
    _Float16* __restrict__ x_h,
    float* __restrict__ tkw, int* __restrict__ lists, int* __restrict__ cnt) {
  __shared__ f64x2 Gs[32 * 64];      // 32 KB, [kp][col] current chunk
  __shared__ double xsd[16][66];     // 8.25 KB
  __shared__ double lg[16 * 64];     // 8 KB
  __shared__ int lcnt[8];
  __shared__ int lbase[8];
  int tid = threadIdx.x, lane = tid & 63, w = tid >> 6;
  int bs0 = blockIdx.x * 16;
  double acc[4];
  #pragma unroll
  for (int r = 0; r < 4; r++) acc[r] = 0.0;
  int xrow = tid >> 4, xc4 = tid & 15;
  const double* xr = &xsd[0][0] + (w * 4) * 66;
  if (tid < 8) lcnt[tid] = 0;

  for (int ch = 0; ch < 16; ch++) {
    __syncthreads();           // previous chunk's reads complete before overwrite
    // stage x chunk (16 rows x 64 k) as double + fused fp16 convert
    float4 xv4 = *(const float4*)(x + (size_t)(bs0 + xrow) * ND + ch * 64 + xc4 * 4);
    f64x2 xa = { (double)xv4.x, (double)xv4.y };
    f64x2 xb = { (double)xv4.z, (double)xv4.w };
    *(f64x2*)&xsd[xrow][xc4 * 4]     = xa;
    *(f64x2*)&xsd[xrow][xc4 * 4 + 2] = xb;
    f16x4 xh = { (_Float16)xv4.x, (_Float16)xv4.y, (_Float16)xv4.z, (_Float16)xv4.w };
    *(f16x4*)(x_h + (size_t)(bs0 + xrow) * ND + ch * 64 + xc4 * 4) = xh;
    // async-stage G chunk: linear 32KB copy, no VGPR round-trip
    #pragma unroll
    for (int j = 0; j < 8; j++) {
      int n = j * 256 + tid;           // 0..2047 16B granules
      gload_lds16(Gx2 + (size_t)ch * 2048 + n, Gs + n);
    }
    __syncthreads();           // compiler drains vmcnt: G + x ready
    #pragma unroll 4
    for (int kp = 0; kp < 32; kp++) {
      f64x2 g = Gs[kp * 64 + lane];        // contiguous 16B/lane: conflict-free
      #pragma unroll
      for (int r = 0; r < 4; r++) {
        f64x2 xv = *(const f64x2*)(xr + r * 66 + kp * 2);   // LDS broadcast
        acc[r] += xv.x * g.x;
        acc[r] += xv.y * g.y;
      }
    }
  }
  double gb = gbias[lane];
  #pragma unroll
  for (int r = 0; r < 4; r++)
    lg[(w * 4 + r) * 64 + lane] = acc[r] + gb;
  __syncthreads();

  int i1 = 0, i2 = 0, token = 0, p1 = 0, p2 = 0;
  if (tid < 128) {
    int row = tid >> 3, h = tid & 7;
    const double* L = lg + row * 64 + h * 8;
    double v1 = L[0];
    #pragma unroll
    for (int e2 = 1; e2 < 8; e2++) if (L[e2] > v1) { v1 = L[e2]; i1 = e2; }
    i2 = -1; double v2 = -1e300;
    #pragma unroll
    for (int e2 = 0; e2 < 8; e2++) if (e2 != i1 && L[e2] > v2) { v2 = L[e2]; i2 = e2; }
    float ex = expf((float)(v2 - v1));        // <= 1
    float den = 1.f + ex;
    float g1 = 1.f / den, g2 = ex / den;
    token = (bs0 + row) * 8 + h;
    tkw[token * 2]     = g1;
    tkw[token * 2 + 1] = g2;
    p1 = atomicAdd(&lcnt[i1], 1);             // LDS atomics: cheap
    p2 = atomicAdd(&lcnt[i2], 1);
  }
  __syncthreads();
  if (tid < 8) lbase[tid] = atomicAdd(cnt + tid * 64, lcnt[tid]);   // 8 global atomics/block
  __syncthreads();
  if (tid < 128) {
    lists[(size_t)i1 * NT + lbase[i1] + p1] = token * 2;
    lists[(size_t)i2 * NT + lbase[i2] + p2] = token * 2 + 1;
  }
}

// C[M][N] = A[M][K] @ Bt[N][K]^T + bias; fp16 inputs, fp32 acc.
// 128x128 tile, BK=32, 4 waves (2x2 of 64x64), global_load_lds width 16.
__global__ __launch_bounds__(256) void gemm_f16_kernel(
    const _Float16* __restrict__ A, const _Float16* __restrict__ Bt,
    const float* __restrict__ bias, float* __restrict__ Cf, _Float16* __restrict__ Ch,
    int M, int N, int Kd) {
  __shared__ _Float16 As[128 * 32];
  __shared__ _Float16 Bs[128 * 32];
  int tid = threadIdx.x, lane = tid & 63, w = tid >> 6;
  int wr = w >> 1, wc = w & 1;
  int m0 = blockIdx.y * 128, n0 = blockIdx.x * 128;
  f32x4 acc[4][4];
  #pragma unroll
  for (int i = 0; i < 4; i++)
    #pragma unroll
    for (int j = 0; j < 4; j++) acc[i][j] = (f32x4){0.f, 0.f, 0.f, 0.f};
  int srow = lane >> 2, scol = (lane & 3) * 8;
  int fr = lane & 15, ko = (lane >> 4) * 8;
  const _Float16* Ag = A + (size_t)(m0 + srow) * Kd + scol;
  const _Float16* Bg = Bt + (size_t)(n0 + srow) * Kd + scol;

  for (int k0 = 0; k0 < Kd; k0 += 32) {
    #pragma unroll
    for (int j = 0; j < 2; j++) {
      int rb = (w * 2 + j) * 16;
      gload_lds16(Ag + (size_t)rb * Kd + k0, As + rb * 32);
      gload_lds16(Bg + (size_t)rb * Kd + k0, Bs + rb * 32);
    }
    __syncthreads();
    f16x8 af[4], bq[4];
    #pragma unroll
    for (int mi = 0; mi < 4; mi++) af[mi] = *(const f16x8*)(As + (wr * 64 + mi * 16 + fr) * 32 + ko);
    #pragma unroll
    for (int ni = 0; ni < 4; ni++) bq[ni] = *(const f16x8*)(Bs + (wc * 64 + ni * 16 + fr) * 32 + ko);
    __syncthreads();
    #pragma unroll
    for (int mi = 0; mi < 4; mi++)
      #pragma unroll
      for (int ni = 0; ni < 4; ni++)
        acc[mi][ni] = __builtin_amdgcn_mfma_f32_16x16x32_f16(af[mi], bq[ni], acc[mi][ni], 0, 0, 0);
  }
  int rbase = m0 + wr * 64 + ((lane >> 4) << 2);
  int cbase = n0 + wc * 64 + (lane & 15);
  #pragma unroll
  for (int mi = 0; mi < 4; mi++)
    #pragma unroll
    for (int ni = 0; ni < 4; ni++) {
      int cc = cbase + ni * 16;
      float bv = bias ? bias[cc] : 0.f;
      #pragma unroll
      for (int r = 0; r < 4; r++) {
        int rr = rbase + mi * 16 + r;
        float v = acc[mi][ni][r] + bv;
        if (Cf) Cf[(size_t)rr * N + cc] = v;
        if (Ch) Ch[(size_t)rr * N + cc] = (_Float16)v;
      }
    }
}

// Grouped expert kernel v9 = v7 + swapped-operand phase A (acc1 = mfma(bq, af)
// computes h^T: reg-quad = 4 consecutive ff for one token -> single b64 h-write).
// 3-ring counted-vmcnt staging; phase B/epilogue as v7.
__global__ __launch_bounds__(512, 2) void expert_kernel(
    const _Float16* __restrict__ t_h, const _Float16* __restrict__ W1t, const _Float16* __restrict__ W2t,
    const float* __restrict__ b1, const float* __restrict__ b2,
    const int* __restrict__ cnt, const int* __restrict__ lists, const float* __restrict__ tkw,
    _Float16* __restrict__ slots) {
  int e = blockIdx.x & 7;              // consecutive blocks -> different XCDs
  int m0 = (blockIdx.x >> 3) * 128;
  int count = cnt[e * 64];
  if (m0 >= count) return;
  __shared__ _Float16 ring[3][64 * 128];  // 3 x 16 KB staging ring
  __shared__ _Float16 h_s[128 * 64];      // 16 KB [tok128][ff64] 128B rows
  __shared__ float b1s[NFF];              // 2 KB
  __shared__ float b2s[HD];               // 512 B
  __shared__ int alist[128];
  __shared__ float aw[128];
  int tid = threadIdx.x, lane = tid & 63, w = tid >> 6;
  int wr = w >> 1, wc = w & 1;         // 4 row-quarters (32) x 2 col-halves (64)
  int fr = lane & 15, g = lane >> 4;

  if (tid < 128) {
    int idx = m0 + tid;
    int a = (idx < count) ? lists[(size_t)e * NT + idx] : -1;
    alist[tid] = a;
    aw[tid] = (a >= 0) ? tkw[a] : 0.f;
  }
  b1s[tid] = b1[e * NFF + tid];
  if (tid < 128) b2s[tid] = b2[e * HD + tid];
  __syncthreads();

  // stage phase p's weights into ring[p%3]. p even: W1 chunk [ff64][d128];
  // p odd: W2 chunk [d128][ff64]. Source pre-swizzled: sg = gg^((r>>1)&7).
  auto stage = [&](int p) {
    if (p >= 16) return;
    int ch = p >> 1;
    _Float16* dst = &ring[p % 3][0];
    if ((p & 1) == 0) {
      #pragma unroll
      for (int j = 0; j < 2; j++) {
        int n = j * 512 + tid;           // 16 granules per 256B row
        int r = n >> 4, gg = n & 15;
        int sg = gg ^ ((r >> 1) & 7);
        gload_lds16(W1t + (size_t)e * (NFF * HD) + (size_t)(ch * 64 + r) * HD + sg * 8, dst + n * 8);
      }
    } else {
      #pragma unroll
      for (int j = 0; j < 2; j++) {
        int n = j * 512 + tid;           // 8 granules per 128B row
        int r = n >> 3, gg = n & 7;
        int sg = gg ^ ((r >> 1) & 7);
        gload_lds16(W2t + (size_t)e * (HD * NFF) + (size_t)r * NFF + ch * 64 + sg * 8, dst + n * 8);
      }
    }
  };

  // gather this wave's 32 token rows into registers (held across all phases)
  f16x8 af[2][4];
  #pragma unroll
  for (int mi = 0; mi < 2; mi++) {
    int rloc = wr * 32 + mi * 16 + fr;
    int a = alist[rloc];
    const _Float16* tb = t_h + (size_t)(a >> 1) * HD;
    #pragma unroll
    for (int ks = 0; ks < 4; ks++) {
      f16x8 v = {0, 0, 0, 0, 0, 0, 0, 0};
      if (a >= 0) v = *(const f16x8*)(tb + ks * 32 + g * 8);
      af[mi][ks] = v;
    }
  }
  asm volatile("s_waitcnt vmcnt(0)" ::: "memory");   // drain gather: loop vmcnt is stage-only
  stage(0); stage(1);
  asm volatile("s_waitcnt vmcnt(2) lgkmcnt(0)\n\ts_barrier" ::: "memory");  // stage(0) landed

  f32x4 acc2[2][4];
  #pragma unroll
  for (int i = 0; i < 2; i++)
    #pragma unroll
    for (int j = 0; j < 4; j++) acc2[i][j] = (f32x4){0.f, 0.f, 0.f, 0.f};

  #pragma unroll
  for (int p = 0; p < 16; p++) {
    stage(p + 2);
    int ch = p >> 1;
    const char* WB = (const char*)&ring[p % 3][0];
    if ((p & 1) == 0) {
      // ---- A (swapped): acc1 = W1^T . t^T = h^T; reg-quad = 4 consecutive ff ----
      float b1r[2][4];
      #pragma unroll
      for (int ni = 0; ni < 2; ni++)
        #pragma unroll
        for (int r = 0; r < 4; r++)
          b1r[ni][r] = b1s[ch * 64 + wc * 32 + ni * 16 + g * 4 + r];
      f32x4 acc1[2][2];    // [mi tok-block][ni ff-block]
      #pragma unroll
      for (int i = 0; i < 2; i++)
        #pragma unroll
        for (int j = 0; j < 2; j++) acc1[i][j] = (f32x4){0.f, 0.f, 0.f, 0.f};
      #pragma unroll
      for (int ks = 0; ks < 4; ks++) {
        f16x8 bq[2];
        #pragma unroll
        for (int ni = 0; ni < 2; ni++) {
          int rw = wc * 32 + ni * 16 + fr;       // ff row of chunk (0..63)
          int byte = rw * 256 + ((ks * 64 + g * 16) ^ (((rw >> 1) & 7) << 4));
          bq[ni] = *(const f16x8*)(WB + byte);
        }
        #pragma unroll
        for (int mi = 0; mi < 2; mi++)
          #pragma unroll
          for (int ni = 0; ni < 2; ni++)
            acc1[mi][ni] = __builtin_amdgcn_mfma_f32_16x16x32_f16(bq[ni], af[mi][ks], acc1[mi][ni], 0, 0, 0);
      }
      // relu + bias -> pack 4 consecutive ff -> single b64 write per (mi,ni)
      #pragma unroll
      for (int mi = 0; mi < 2; mi++)
        #pragma unroll
        for (int ni = 0; ni < 2; ni++) {
          f16x4 hv;
          #pragma unroll
          for (int r = 0; r < 4; r++)
            hv[r] = (_Float16)fmaxf(acc1[mi][ni][r] + b1r[ni][r], 0.f);
          int tok = wr * 32 + mi * 16 + fr;
          int foff = wc * 64 + ni * 32 + g * 8;       // ff*2 bytes
          int byte = tok * 128 + (foff ^ (((tok >> 1) & 7) << 4));
          *(f16x4*)((char*)h_s + byte) = hv;
        }
    } else {
      // ---- B: acc2 += h(:, ch) @ W2chunk (unchanged from v7) ----
      #pragma unroll
      for (int ks = 0; ks < 2; ks++) {
        f16x8 ah[2], bq[4];
        #pragma unroll
        for (int mi = 0; mi < 2; mi++) {
          int row = wr * 32 + mi * 16 + fr;
          int byte = row * 128 + ((ks * 64 + g * 16) ^ (((row >> 1) & 7) << 4));
          ah[mi] = *(const f16x8*)((const char*)h_s + byte);
        }
        #pragma unroll
        for (int ni = 0; ni < 4; ni++) {
          int rw = wc * 64 + ni * 16 + fr;       // d row (0..127)
          int byte = rw * 128 + ((ks * 64 + g * 16) ^ (((rw >> 1) & 7) << 4));
          bq[ni] = *(const f16x8*)((const char*)&ring[p % 3][0] + byte);
        }
        #pragma unroll
        for (int mi = 0; mi < 2; mi++)
          #pragma unroll
          for (int ni = 0; ni < 4; ni++)
            acc2[mi][ni] = __builtin_amdgcn_mfma_f32_16x16x32_f16(ah[mi], bq[ni], acc2[mi][ni], 0, 0, 0);
      }
    }
    // phase sync: next phase's weights landed (counted), h_s coherent.
    if (p == 14) {
      asm volatile("s_waitcnt vmcnt(0) lgkmcnt(0)\n\ts_barrier" ::: "memory");
    } else if (p < 14) {
      asm volatile("s_waitcnt vmcnt(2) lgkmcnt(0)\n\ts_barrier" ::: "memory");
    }
  }
  // epilogue: gate-scale + fp16 scatter to slots
  #pragma unroll
  for (int mi = 0; mi < 2; mi++)
    #pragma unroll
    for (int ni = 0; ni < 4; ni++) {
      int ncol = wc * 64 + ni * 16 + fr;
      float bv = b2s[ncol];
      #pragma unroll
      for (int r = 0; r < 4; r++) {
        int m = wr * 32 + mi * 16 + g * 4 + r;
        int a = alist[m];
        if (a >= 0)
          slots[(size_t)a * HD + ncol] = (_Float16)(aw[m] * (acc2[mi][ni][r] + bv));
      }
    }
}

// combine slots -> momentum update -> residual -> LayerNorm; writes nm_out (fp32) + out_h (fp16)
// 1 wave per token (2 elems/lane), 4 tokens/block
__global__ __launch_bounds__(256) void combine_ln_kernel(
    const _Float16* __restrict__ slots, const float* __restrict__ momentum,
    const _Float16* __restrict__ t_h, const float* __restrict__ ln_g, const float* __restrict__ ln_b,
    float* __restrict__ nm_out, _Float16* __restrict__ out_h) {
  int w = threadIdx.x >> 6, lane = threadIdx.x & 63;
  int tok = blockIdx.x * 4 + w;
  int d0 = lane * 2;
  f16x2 s0 = *(const f16x2*)(slots + (size_t)tok * 256 + d0);
  f16x2 s1 = *(const f16x2*)(slots + (size_t)tok * 256 + 128 + d0);
  float2 mo = *(const float2*)(momentum + (size_t)tok * HD + d0);
  f16x2 tv = *(const f16x2*)(t_h + (size_t)tok * HD + d0);
  float nm0 = -((float)s0.x + (float)s1.x) + MU_F * mo.x;
  float nm1 = -((float)s0.y + (float)s1.y) + MU_F * mo.y;
  float2 nm2; nm2.x = nm0; nm2.y = nm1;
  *(float2*)(nm_out + (size_t)tok * HD + d0) = nm2;
  float r0 = (float)tv.x + nm0;
  float r1 = (float)tv.y + nm1;
  float s = r0 + r1, sq = r0 * r0 + r1 * r1;
  #pragma unroll
  for (int m = 1; m < 64; m <<= 1) { s += __shfl_xor(s, m, 64); sq += __shfl_xor(sq, m, 64); }
  float mean = s * (1.f / 128.f);
  float var = sq * (1.f / 128.f) - mean * mean;
  float is = rsqrtf(var + LN_EPS_F);
  float y0 = (r0 - mean) * is * ln_g[d0] + ln_b[d0];
  float y1 = (r1 - mean) * is * ln_g[d0 + 1] + ln_b[d0 + 1];
  f16x2 yo = { (_Float16)y0, (_Float16)y1 };
  *(f16x2*)(out_h + (size_t)tok * HD + d0) = yo;
}

extern "C" void kernel_launch(void* const* d_in, const int* in_sizes, int n_in,
                              void* d_out, int out_size, void* d_ws, size_t ws_size,
                              hipStream_t stream) {
  const float* x        = (const float*)d_in[0];
  const float* momentum = (const float*)d_in[1];
  const float* split_W  = (const float*)d_in[2];
  const float* split_b  = (const float*)d_in[3];
  const float* gate_W   = (const float*)d_in[4];
  const float* gate_b   = (const float*)d_in[5];
  const float* W1       = (const float*)d_in[6];
  const float* b1       = (const float*)d_in[7];
  const float* W2       = (const float*)d_in[8];
  const float* b2       = (const float*)d_in[9];
  const float* ln_g     = (const float*)d_in[10];
  const float* ln_b     = (const float*)d_in[11];
  const float* merge_W  = (const float*)d_in[12];
  const float* merge_b  = (const float*)d_in[13];
  float* final_out = (float*)d_out;
  float* nm_out    = final_out + (size_t)NBS * ND;

  char* ws = (char*)d_ws;
  size_t off = 0;
  auto alloc = [&](size_t bytes) { void* p = ws + off; off = (off + bytes + 255) & ~(size_t)255; return p; };
  _Float16* x_h   = (_Float16*)alloc((size_t)NBS * ND * 2);
  _Float16* t_h   = (_Float16*)alloc((size_t)NT * HD * 2);
  _Float16* out_h = (_Float16*)alloc((size_t)NT * HD * 2);
  _Float16* sWt   = (_Float16*)alloc((size_t)ND * ND * 2);
  _Float16* mWt   = (_Float16*)alloc((size_t)ND * ND * 2);
  _Float16* W1t   = (_Float16*)alloc((size_t)NE * HD * NFF * 2);
  _Float16* W2t   = (_Float16*)alloc((size_t)NE * HD * NFF * 2);
  f64x2*    Gx2   = (f64x2*)alloc((size_t)512 * 64 * 16);
  double*   gbias = (double*)alloc(64 * 8);
  float*    tkw   = (float*)alloc((size_t)NT * 2 * 4);
  int*      lists = (int*)alloc((size_t)NE * NT * 4);
  int*      cnt   = (int*)alloc(512 * 4);
  _Float16* slots = (_Float16*)alloc((size_t)NT * 2 * HD * 2);
  (void)in_sizes; (void)n_in; (void)out_size; (void)ws_size;

  zero_cnt_kernel<<<1, 512, 0, stream>>>(cnt);
  tr_cvt_kernel<<<dim3(32, 32, 1), dim3(32, 8), 0, stream>>>(split_W, sWt, ND, ND);
  tr_cvt_kernel<<<dim3(32, 32, 1), dim3(32, 8), 0, stream>>>(merge_W, mWt, ND, ND);
  tr_cvt_kernel<<<dim3(16, 4, 8), dim3(32, 8), 0, stream>>>(W1, W1t, HD, NFF);
  tr_cvt_kernel<<<dim3(4, 16, 8), dim3(32, 8), 0, stream>>>(W2, W2t, NFF, HD);
  build_G_kernel<<<256, 256, 0, stream>>>(split_W, split_b, gate_W, gate_b, (double*)Gx2, gbias);
  // gate also produces x_h (fused convert), so it runs before the split GEMM
  gate_kernel<<<512, 256, 0, stream>>>(x, Gx2, gbias, x_h, tkw, lists, cnt);
  // t = x @ split_W + split_b   (fp16 out for downstream MFMA)
  gemm_f16_kernel<<<dim3(8, 64), 256, 0, stream>>>(x_h, sWt, split_b, nullptr, t_h, NBS, ND, ND);
  expert_kernel<<<NE * 512, 512, 0, stream>>>(t_h, W1t, W2t, b1, b2, cnt, lists, tkw, slots);
  combine_ln_kernel<<<NT / 4, 256, 0, stream>>>(slots, momentum, t_h, ln_g, ln_b, nm_out, out_h);
  // final = out @ merge_W + merge_b
  gemm_f16_kernel<<<dim3(8, 64), 256, 0, stream>>>(out_h, mWt, merge_b, final_out, nullptr, NBS, ND, ND);
}

// Round 14
// 237.903 us; speedup vs baseline: 1.1437x; 1.0098x over previous
//
#include <hip/hip_runtime.h>

#define NBATCH 4
#define NS 2048
#define ND 1024
#define NH 8
#define HD 128
#define NFF 512
#define NE 8
#define NT 65536       /* B*S*H tokens */
#define NBS 8192       /* B*S rows */
#define MU_F 0.7f
#define LN_EPS_F 1e-5f

typedef __attribute__((ext_vector_type(4))) float f32x4;
typedef __attribute__((ext_vector_type(2))) double f64x2;
typedef __attribute__((ext_vector_type(8))) _Float16 f16x8;
typedef __attribute__((ext_vector_type(4))) _Float16 f16x4;
typedef __attribute__((ext_vector_type(2))) _Float16 f16x2;

__device__ __forceinline__ void gload_lds16(const void* g, void* l) {
  __builtin_amdgcn_global_load_lds(
      (const __attribute__((address_space(1))) unsigned int*)g,
      (__attribute__((address_space(3))) unsigned int*)l, 16, 0, 0);
}

// batched transpose + convert: in [batch][R][C] f32 -> out [batch][C][R] f16
// R, C multiples of 32. block (32,8), grid (C/32, R/32, batch)
__global__ void tr_cvt_kernel(const float* __restrict__ in, _Float16* __restrict__ out, int R, int C) {
  __shared__ float tile[32][33];
  int b = blockIdx.z;
  const float* inp = in + (size_t)b * R * C;
  _Float16* outp = out + (size_t)b * R * C;
  int c = blockIdx.x * 32 + threadIdx.x;
  int r0 = blockIdx.y * 32;
  #pragma unroll
  for (int i = 0; i < 4; i++) {
    int r = r0 + threadIdx.y + i * 8;
    tile[threadIdx.y + i * 8][threadIdx.x] = inp[(size_t)r * C + c];
  }
  __syncthreads();
  int rr = r0 + threadIdx.x;
  #pragma unroll
  for (int i = 0; i < 4; i++) {
    int cc = blockIdx.x * 32 + threadIdx.y + i * 8;
    outp[(size_t)cc * R + rr] = (_Float16)tile[threadIdx.x][threadIdx.y + i * 8];
  }
}

// one thread per G[d][o] scalar (65536 threads = 256 blocks, full GPU).
// Writes directly in Gx2 [kp][o] f64x2 layout. Also zeroes cnt (folds the
// old zero_cnt launch).
__global__ void build_G_kernel(const float* __restrict__ split_W, const float* __restrict__ split_b,
                               const float* __restrict__ gate_W, const float* __restrict__ gate_b,
                               double* __restrict__ G, double* __restrict__ gbias,
                               int* __restrict__ cnt) {
  int idx = blockIdx.x * 256 + threadIdx.x;   // = d*64 + o
  if (blockIdx.x == 0 && threadIdx.x < 256) { cnt[threadIdx.x] = 0; cnt[threadIdx.x + 256] = 0; }
  int d = idx >> 6, o = idx & 63, h = o >> 3, e = o & 7;
  double acc = 0.0;
  const float* r0 = split_W + (size_t)d * ND + h * 128;
  #pragma unroll 4
  for (int j = 0; j < 128; j++)
    acc += (double)r0[j] * (double)gate_W[j * 8 + e];
  G[((size_t)(d >> 1) * 64 + o) * 2 + (d & 1)] = acc;
  if (idx < 64) {
    double bacc = 0.0;
    for (int j = 0; j < 128; j++)
      bacc += (double)split_b[h * 128 + j] * (double)gate_W[j * 8 + e];
    gbias[idx] = bacc + (double)gate_b[e];
  }
}

// fp64 logits = x @ G + gbias, top-2 per (row,h), softmax, per-expert lists.
// v7: COUNTED-VMCNT 3-RING for G (and x) staging -- v6's __syncthreads drained
// vmcnt(0) every chunk, serializing each 32KB stage at full L2 latency (expert
// v7 pattern, proven). 32 chunks of 32 d; per chunk: stage(ch+2) [x: 1 f32x4
// load + f16x4 store + xsd write per <128 thread; G: 4 gload_lds16], compute(ch),
// asm vmcnt(4)+s_barrier (4 = G(ch+2) in flight; x_h stores are OLDER than them
// so in-order vmcnt retirement guarantees G(ch+1)+stores drained regardless of
// compiler reordering). Ring-reuse safe: stage(p+2) buffer's last readers
// passed the end-of-(p-1) barrier. Fused x->fp16 + hierarchical atomics kept.
__global__ __launch_bounds__(256) void gate_kernel(const float* __restrict__ x,
    const f64x2* __restrict__ Gx2, const double* __restrict__ gbias,
    _Float16* __restrict__ x_h,
    float* __restrict__ tkw, int* __restrict__ lists, int* __restrict__ cnt) {
  __shared__ f64x2 Gs[3][16 * 64];      // 3 x 16 KB G ring
  __shared__ double xsd[3][16 * 34];    // 3 x 4.25 KB x ring (34 stride: 16B-aligned f64x2)
  __shared__ double lg[16 * 64];        // 8 KB
  __shared__ int lcnt[8];
  __shared__ int lbase[8];
  int tid = threadIdx.x, lane = tid & 63, w = tid >> 6;
  int bs0 = blockIdx.x * 16;
  double acc[4];
  #pragma unroll
  for (int r = 0; r < 4; r++) acc[r] = 0.0;
  if (tid < 8) lcnt[tid] = 0;

  auto stageX = [&](int ch) {   // 16 rows x 32 d: fp64 to xsd ring + fused f16 convert
    if (tid < 128) {
      int xrow = tid >> 3, c4 = tid & 7;
      float4 xv4 = *(const float4*)(x + (size_t)(bs0 + xrow) * ND + ch * 32 + c4 * 4);
      double* xd = &xsd[ch % 3][0] + xrow * 34 + c4 * 4;
      f64x2 xa = { (double)xv4.x, (double)xv4.y };
      f64x2 xb = { (double)xv4.z, (double)xv4.w };
      *(f64x2*)xd = xa;
      *(f64x2*)(xd + 2) = xb;
      f16x4 xh = { (_Float16)xv4.x, (_Float16)xv4.y, (_Float16)xv4.z, (_Float16)xv4.w };
      *(f16x4*)(x_h + (size_t)(bs0 + xrow) * ND + ch * 32 + c4 * 4) = xh;
    }
  };
  auto stageG = [&](int ch) {   // 16 kp x 64 cols = 1024 granules, linear
    #pragma unroll
    for (int j = 0; j < 4; j++) {
      int n = j * 256 + tid;
      gload_lds16(Gx2 + (size_t)ch * 1024 + n, &Gs[ch % 3][0] + n);
    }
  };

  stageX(0); stageG(0);
  stageX(1); stageG(1);
  asm volatile("s_waitcnt vmcnt(4) lgkmcnt(0)\n\ts_barrier" ::: "memory");  // chunk0 landed

  for (int ch = 0; ch < 32; ch++) {
    if (ch < 30) { stageX(ch + 2); stageG(ch + 2); }
    const f64x2* Gc = &Gs[ch % 3][0];
    const double* xr = &xsd[ch % 3][0] + (w * 4) * 34;
    #pragma unroll 4
    for (int kp = 0; kp < 16; kp++) {
      f64x2 g = Gc[kp * 64 + lane];        // contiguous 16B/lane: conflict-free
      #pragma unroll
      for (int r = 0; r < 4; r++) {
        f64x2 xv = *(const f64x2*)(xr + r * 34 + kp * 2);   // LDS broadcast
        acc[r] += xv.x * g.x;
        acc[r] += xv.y * g.y;
      }
    }
    if (ch < 30) {
      asm volatile("s_waitcnt vmcnt(4) lgkmcnt(0)\n\ts_barrier" ::: "memory");  // G(ch+1) landed
    } else {
      asm volatile("s_waitcnt vmcnt(0) lgkmcnt(0)\n\ts_barrier" ::: "memory");
    }
  }
  double gb = gbias[lane];
  #pragma unroll
  for (int r = 0; r < 4; r++)
    lg[(w * 4 + r) * 64 + lane] = acc[r] + gb;
  __syncthreads();

  int i1 = 0, i2 = 0, token = 0, p1 = 0, p2 = 0;
  if (tid < 128) {
    int row = tid >> 3, h = tid & 7;
    const double* L = lg + row * 64 + h * 8;
    double v1 = L[0];
    #pragma unroll
    for (int e2 = 1; e2 < 8; e2++) if (L[e2] > v1) { v1 = L[e2]; i1 = e2; }
    i2 = -1; double v2 = -1e300;
    #pragma unroll
    for (int e2 = 0; e2 < 8; e2++) if (e2 != i1 && L[e2] > v2) { v2 = L[e2]; i2 = e2; }
    float ex = expf((float)(v2 - v1));        // <= 1
    float den = 1.f + ex;
    float g1 = 1.f / den, g2 = ex / den;
    token = (bs0 + row) * 8 + h;
    tkw[token * 2]     = g1;
    tkw[token * 2 + 1] = g2;
    p1 = atomicAdd(&lcnt[i1], 1);             // LDS atomics: cheap
    p2 = atomicAdd(&lcnt[i2], 1);
  }
  __syncthreads();
  if (tid < 8) lbase[tid] = atomicAdd(cnt + tid * 64, lcnt[tid]);   // 8 global atomics/block
  __syncthreads();
  if (tid < 128) {
    lists[(size_t)i1 * NT + lbase[i1] + p1] = token * 2;
    lists[(size_t)i2 * NT + lbase[i2] + p2] = token * 2 + 1;
  }
}

// C[M][N] = A[M][K] @ Bt[N][K]^T + bias; fp16 inputs, fp32 acc.
// 128x128 tile, BK=32, 4 waves (2x2 of 64x64), global_load_lds width 16.
// v2: XCD-chunked bijective block swizzle (T1): dispatch id l -> XCD l&7 owns
// 8 contiguous A-row-panels (2MB) -> A+B L2-resident per XCD. Grid fixed (8,64).
__global__ __launch_bounds__(256) void gemm_f16_kernel(
    const _Float16* __restrict__ A, const _Float16* __restrict__ Bt,
    const float* __restrict__ bias, float* __restrict__ Cf, _Float16* __restrict__ Ch,
    int M, int N, int Kd) {
  __shared__ _Float16 As[128 * 32];
  __shared__ _Float16 Bs[128 * 32];
  int tid = threadIdx.x, lane = tid & 63, w = tid >> 6;
  int wr = w >> 1, wc = w & 1;
  int lid = blockIdx.y * 8 + blockIdx.x;        // dispatch order (x fastest)
  int xcd = lid & 7, sub = (lid >> 3) & 7, grp = lid >> 6;
  int m0 = (xcd * 8 + sub) * 128;               // contiguous A-panels per XCD
  int n0 = grp * 128;
  f32x4 acc[4][4];
  #pragma unroll
  for (int i = 0; i < 4; i++)
    #pragma unroll
    for (int j = 0; j < 4; j++) acc[i][j] = (f32x4){0.f, 0.f, 0.f, 0.f};
  int srow = lane >> 2, scol = (lane & 3) * 8;
  int fr = lane & 15, ko = (lane >> 4) * 8;
  const _Float16* Ag = A + (size_t)(m0 + srow) * Kd + scol;
  const _Float16* Bg = Bt + (size_t)(n0 + srow) * Kd + scol;

  for (int k0 = 0; k0 < Kd; k0 += 32) {
    #pragma unroll
    for (int j = 0; j < 2; j++) {
      int rb = (w * 2 + j) * 16;
      gload_lds16(Ag + (size_t)rb * Kd + k0, As + rb * 32);
      gload_lds16(Bg + (size_t)rb * Kd + k0, Bs + rb * 32);
    }
    __syncthreads();
    f16x8 af[4], bq[4];
    #pragma unroll
    for (int mi = 0; mi < 4; mi++) af[mi] = *(const f16x8*)(As + (wr * 64 + mi * 16 + fr) * 32 + ko);
    #pragma unroll
    for (int ni = 0; ni < 4; ni++) bq[ni] = *(const f16x8*)(Bs + (wc * 64 + ni * 16 + fr) * 32 + ko);
    __syncthreads();
    #pragma unroll
    for (int mi = 0; mi < 4; mi++)
      #pragma unroll
      for (int ni = 0; ni < 4; ni++)
        acc[mi][ni] = __builtin_amdgcn_mfma_f32_16x16x32_f16(af[mi], bq[ni], acc[mi][ni], 0, 0, 0);
  }
  int rbase = m0 + wr * 64 + ((lane >> 4) << 2);
  int cbase = n0 + wc * 64 + (lane & 15);
  #pragma unroll
  for (int mi = 0; mi < 4; mi++)
    #pragma unroll
    for (int ni = 0; ni < 4; ni++) {
      int cc = cbase + ni * 16;
      float bv = bias ? bias[cc] : 0.f;
      #pragma unroll
      for (int r = 0; r < 4; r++) {
        int rr = rbase + mi * 16 + r;
        float v = acc[mi][ni][r] + bv;
        if (Cf) Cf[(size_t)rr * N + cc] = v;
        if (Ch) Ch[(size_t)rr * N + cc] = (_Float16)v;
      }
    }
}

// Grouped expert kernel v9 = v7 + swapped-operand phase A (acc1 = mfma(bq, af)
// computes h^T: reg-quad = 4 consecutive ff for one token -> single b64 h-write).
// 3-ring counted-vmcnt staging; phase B/epilogue as v7.
__global__ __launch_bounds__(512, 2) void expert_kernel(
    const _Float16* __restrict__ t_h, const _Float16* __restrict__ W1t, const _Float16* __restrict__ W2t,
    const float* __restrict__ b1, const float* __restrict__ b2,
    const int* __restrict__ cnt, const int* __restrict__ lists, const float* __restrict__ tkw,
    _Float16* __restrict__ slots) {
  int e = blockIdx.x & 7;              // consecutive blocks -> different XCDs
  int m0 = (blockIdx.x >> 3) * 128;
  int count = cnt[e * 64];
  if (m0 >= count) return;
  __shared__ _Float16 ring[3][64 * 128];  // 3 x 16 KB staging ring
  __shared__ _Float16 h_s[128 * 64];      // 16 KB [tok128][ff64] 128B rows
  __shared__ float b1s[NFF];              // 2 KB
  __shared__ float b2s[HD];               // 512 B
  __shared__ int alist[128];
  __shared__ float aw[128];
  int tid = threadIdx.x, lane = tid & 63, w = tid >> 6;
  int wr = w >> 1, wc = w & 1;         // 4 row-quarters (32) x 2 col-halves (64)
  int fr = lane & 15, g = lane >> 4;

  if (tid < 128) {
    int idx = m0 + tid;
    int a = (idx < count) ? lists[(size_t)e * NT + idx] : -1;
    alist[tid] = a;
    aw[tid] = (a >= 0) ? tkw[a] : 0.f;
  }
  b1s[tid] = b1[e * NFF + tid];
  if (tid < 128) b2s[tid] = b2[e * HD + tid];
  __syncthreads();

  // stage phase p's weights into ring[p%3]. p even: W1 chunk [ff64][d128];
  // p odd: W2 chunk [d128][ff64]. Source pre-swizzled: sg = gg^((r>>1)&7).
  auto stage = [&](int p) {
    if (p >= 16) return;
    int ch = p >> 1;
    _Float16* dst = &ring[p % 3][0];
    if ((p & 1) == 0) {
      #pragma unroll
      for (int j = 0; j < 2; j++) {
        int n = j * 512 + tid;           // 16 granules per 256B row
        int r = n >> 4, gg = n & 15;
        int sg = gg ^ ((r >> 1) & 7);
        gload_lds16(W1t + (size_t)e * (NFF * HD) + (size_t)(ch * 64 + r) * HD + sg * 8, dst + n * 8);
      }
    } else {
      #pragma unroll
      for (int j = 0; j < 2; j++) {
        int n = j * 512 + tid;           // 8 granules per 128B row
        int r = n >> 3, gg = n & 7;
        int sg = gg ^ ((r >> 1) & 7);
        gload_lds16(W2t + (size_t)e * (HD * NFF) + (size_t)r * NFF + ch * 64 + sg * 8, dst + n * 8);
      }
    }
  };

  // gather this wave's 32 token rows into registers (held across all phases)
  f16x8 af[2][4];
  #pragma unroll
  for (int mi = 0; mi < 2; mi++) {
    int rloc = wr * 32 + mi * 16 + fr;
    int a = alist[rloc];
    const _Float16* tb = t_h + (size_t)(a >> 1) * HD;
    #pragma unroll
    for (int ks = 0; ks < 4; ks++) {
      f16x8 v = {0, 0, 0, 0, 0, 0, 0, 0};
      if (a >= 0) v = *(const f16x8*)(tb + ks * 32 + g * 8);
      af[mi][ks] = v;
    }
  }
  asm volatile("s_waitcnt vmcnt(0)" ::: "memory");   // drain gather: loop vmcnt is stage-only
  stage(0); stage(1);
  asm volatile("s_waitcnt vmcnt(2) lgkmcnt(0)\n\ts_barrier" ::: "memory");  // stage(0) landed

  f32x4 acc2[2][4];
  #pragma unroll
  for (int i = 0; i < 2; i++)
    #pragma unroll
    for (int j = 0; j < 4; j++) acc2[i][j] = (f32x4){0.f, 0.f, 0.f, 0.f};

  #pragma unroll
  for (int p = 0; p < 16; p++) {
    stage(p + 2);
    int ch = p >> 1;
    const char* WB = (const char*)&ring[p % 3][0];
    if ((p & 1) == 0) {
      // ---- A (swapped): acc1 = W1^T . t^T = h^T; reg-quad = 4 consecutive ff ----
      float b1r[2][4];
      #pragma unroll
      for (int ni = 0; ni < 2; ni++)
        #pragma unroll
        for (int r = 0; r < 4; r++)
          b1r[ni][r] = b1s[ch * 64 + wc * 32 + ni * 16 + g * 4 + r];
      f32x4 acc1[2][2];    // [mi tok-block][ni ff-block]
      #pragma unroll
      for (int i = 0; i < 2; i++)
        #pragma unroll
        for (int j = 0; j < 2; j++) acc1[i][j] = (f32x4){0.f, 0.f, 0.f, 0.f};
      #pragma unroll
      for (int ks = 0; ks < 4; ks++) {
        f16x8 bq[2];
        #pragma unroll
        for (int ni = 0; ni < 2; ni++) {
          int rw = wc * 32 + ni * 16 + fr;       // ff row of chunk (0..63)
          int byte = rw * 256 + ((ks * 64 + g * 16) ^ (((rw >> 1) & 7) << 4));
          bq[ni] = *(const f16x8*)(WB + byte);
        }
        #pragma unroll
        for (int mi = 0; mi < 2; mi++)
          #pragma unroll
          for (int ni = 0; ni < 2; ni++)
            acc1[mi][ni] = __builtin_amdgcn_mfma_f32_16x16x32_f16(bq[ni], af[mi][ks], acc1[mi][ni], 0, 0, 0);
      }
      // relu + bias -> pack 4 consecutive ff -> single b64 write per (mi,ni)
      #pragma unroll
      for (int mi = 0; mi < 2; mi++)
        #pragma unroll
        for (int ni = 0; ni < 2; ni++) {
          f16x4 hv;
          #pragma unroll
          for (int r = 0; r < 4; r++)
            hv[r] = (_Float16)fmaxf(acc1[mi][ni][r] + b1r[ni][r], 0.f);
          int tok = wr * 32 + mi * 16 + fr;
          int foff = wc * 64 + ni * 32 + g * 8;       // ff*2 bytes
          int byte = tok * 128 + (foff ^ (((tok >> 1) & 7) << 4));
          *(f16x4*)((char*)h_s + byte) = hv;
        }
    } else {
      // ---- B: acc2 += h(:, ch) @ W2chunk (unchanged from v7) ----
      #pragma unroll
      for (int ks = 0; ks < 2; ks++) {
        f16x8 ah[2], bq[4];
        #pragma unroll
        for (int mi = 0; mi < 2; mi++) {
          int row = wr * 32 + mi * 16 + fr;
          int byte = row * 128 + ((ks * 64 + g * 16) ^ (((row >> 1) & 7) << 4));
          ah[mi] = *(const f16x8*)((const char*)h_s + byte);
        }
        #pragma unroll
        for (int ni = 0; ni < 4; ni++) {
          int rw = wc * 64 + ni * 16 + fr;       // d row (0..127)
          int byte = rw * 128 + ((ks * 64 + g * 16) ^ (((rw >> 1) & 7) << 4));
          bq[ni] = *(const f16x8*)((const char*)&ring[p % 3][0] + byte);
        }
        #pragma unroll
        for (int mi = 0; mi < 2; mi++)
          #pragma unroll
          for (int ni = 0; ni < 4; ni++)
            acc2[mi][ni] = __builtin_amdgcn_mfma_f32_16x16x32_f16(ah[mi], bq[ni], acc2[mi][ni], 0, 0, 0);
      }
    }
    // phase sync: next phase's weights landed (counted), h_s coherent.
    if (p == 14) {
      asm volatile("s_waitcnt vmcnt(0) lgkmcnt(0)\n\ts_barrier" ::: "memory");
    } else if (p < 14) {
      asm volatile("s_waitcnt vmcnt(2) lgkmcnt(0)\n\ts_barrier" ::: "memory");
    }
  }
  // epilogue: gate-scale + fp16 scatter to slots
  #pragma unroll
  for (int mi = 0; mi < 2; mi++)
    #pragma unroll
    for (int ni = 0; ni < 4; ni++) {
      int ncol = wc * 64 + ni * 16 + fr;
      float bv = b2s[ncol];
      #pragma unroll
      for (int r = 0; r < 4; r++) {
        int m = wr * 32 + mi * 16 + g * 4 + r;
        int a = alist[m];
        if (a >= 0)
          slots[(size_t)a * HD + ncol] = (_Float16)(aw[m] * (acc2[mi][ni][r] + bv));
      }
    }
}

// combine slots -> momentum update -> residual -> LayerNorm; writes nm_out (fp32) + out_h (fp16)
// 1 wave per token (2 elems/lane), 4 tokens/block
__global__ __launch_bounds__(256) void combine_ln_kernel(
    const _Float16* __restrict__ slots, const float* __restrict__ momentum,
    const _Float16* __restrict__ t_h, const float* __restrict__ ln_g, const float* __restrict__ ln_b,
    float* __restrict__ nm_out, _Float16* __restrict__ out_h) {
  int w = threadIdx.x >> 6, lane = threadIdx.x & 63;
  int tok = blockIdx.x * 4 + w;
  int d0 = lane * 2;
  f16x2 s0 = *(const f16x2*)(slots + (size_t)tok * 256 + d0);
  f16x2 s1 = *(const f16x2*)(slots + (size_t)tok * 256 + 128 + d0);
  float2 mo = *(const float2*)(momentum + (size_t)tok * HD + d0);
  f16x2 tv = *(const f16x2*)(t_h + (size_t)tok * HD + d0);
  float nm0 = -((float)s0.x + (float)s1.x) + MU_F * mo.x;
  float nm1 = -((float)s0.y + (float)s1.y) + MU_F * mo.y;
  float2 nm2; nm2.x = nm0; nm2.y = nm1;
  *(float2*)(nm_out + (size_t)tok * HD + d0) = nm2;
  float r0 = (float)tv.x + nm0;
  float r1 = (float)tv.y + nm1;
  float s = r0 + r1, sq = r0 * r0 + r1 * r1;
  #pragma unroll
  for (int m = 1; m < 64; m <<= 1) { s += __shfl_xor(s, m, 64); sq += __shfl_xor(sq, m, 64); }
  float mean = s * (1.f / 128.f);
  float var = sq * (1.f / 128.f) - mean * mean;
  float is = rsqrtf(var + LN_EPS_F);
  float y0 = (r0 - mean) * is * ln_g[d0] + ln_b[d0];
  float y1 = (r1 - mean) * is * ln_g[d0 + 1] + ln_b[d0 + 1];
  f16x2 yo = { (_Float16)y0, (_Float16)y1 };
  *(f16x2*)(out_h + (size_t)tok * HD + d0) = yo;
}

extern "C" void kernel_launch(void* const* d_in, const int* in_sizes, int n_in,
                              void* d_out, int out_size, void* d_ws, size_t ws_size,
                              hipStream_t stream) {
  const float* x        = (const float*)d_in[0];
  const float* momentum = (const float*)d_in[1];
  const float* split_W  = (const float*)d_in[2];
  const float* split_b  = (const float*)d_in[3];
  const float* gate_W   = (const float*)d_in[4];
  const float* gate_b   = (const float*)d_in[5];
  const float* W1       = (const float*)d_in[6];
  const float* b1       = (const float*)d_in[7];
  const float* W2       = (const float*)d_in[8];
  const float* b2       = (const float*)d_in[9];
  const float* ln_g     = (const float*)d_in[10];
  const float* ln_b     = (const float*)d_in[11];
  const float* merge_W  = (const float*)d_in[12];
  const float* merge_b  = (const float*)d_in[13];
  float* final_out = (float*)d_out;
  float* nm_out    = final_out + (size_t)NBS * ND;

  char* ws = (char*)d_ws;
  size_t off = 0;
  auto alloc = [&](size_t bytes) { void* p = ws + off; off = (off + bytes + 255) & ~(size_t)255; return p; };
  _Float16* x_h   = (_Float16*)alloc((size_t)NBS * ND * 2);
  _Float16* t_h   = (_Float16*)alloc((size_t)NT * HD * 2);
  _Float16* out_h = (_Float16*)alloc((size_t)NT * HD * 2);
  _Float16* sWt   = (_Float16*)alloc((size_t)ND * ND * 2);
  _Float16* mWt   = (_Float16*)alloc((size_t)ND * ND * 2);
  _Float16* W1t   = (_Float16*)alloc((size_t)NE * HD * NFF * 2);
  _Float16* W2t   = (_Float16*)alloc((size_t)NE * HD * NFF * 2);
  f64x2*    Gx2   = (f64x2*)alloc((size_t)512 * 64 * 16);
  double*   gbias = (double*)alloc(64 * 8);
  float*    tkw   = (float*)alloc((size_t)NT * 2 * 4);
  int*      lists = (int*)alloc((size_t)NE * NT * 4);
  int*      cnt   = (int*)alloc(512 * 4);
  _Float16* slots = (_Float16*)alloc((size_t)NT * 2 * HD * 2);
  (void)in_sizes; (void)n_in; (void)out_size; (void)ws_size;

  tr_cvt_kernel<<<dim3(32, 32, 1), dim3(32, 8), 0, stream>>>(split_W, sWt, ND, ND);
  tr_cvt_kernel<<<dim3(32, 32, 1), dim3(32, 8), 0, stream>>>(merge_W, mWt, ND, ND);
  tr_cvt_kernel<<<dim3(16, 4, 8), dim3(32, 8), 0, stream>>>(W1, W1t, HD, NFF);
  tr_cvt_kernel<<<dim3(4, 16, 8), dim3(32, 8), 0, stream>>>(W2, W2t, NFF, HD);
  build_G_kernel<<<256, 256, 0, stream>>>(split_W, split_b, gate_W, gate_b, (double*)Gx2, gbias, cnt);
  // gate also produces x_h (fused convert), so it runs before the split GEMM
  gate_kernel<<<512, 256, 0, stream>>>(x, Gx2, gbias, x_h, tkw, lists, cnt);
  // t = x @ split_W + split_b   (fp16 out for downstream MFMA)
  gemm_f16_kernel<<<dim3(8, 64), 256, 0, stream>>>(x_h, sWt, split_b, nullptr, t_h, NBS, ND, ND);
  expert_kernel<<<NE * 512, 512, 0, stream>>>(t_h, W1t, W2t, b1, b2, cnt, lists, tkw, slots);
  combine_ln_kernel<<<NT / 4, 256, 0, stream>>>(slots, momentum, t_h, ln_g, ln_b, nm_out, out_h);
  // final = out @ merge_W + merge_b
  gemm_f16_kernel<<<dim3(8, 64), 256, 0, stream>>>(out_h, mWt, merge_b, final_out, nullptr, NBS, ND, ND);
}

// Round 16
// 235.102 us; speedup vs baseline: 1.1573x; 1.0119x over previous
//
#include <hip/hip_runtime.h>

#define NBATCH 4
#define NS 2048
#define ND 1024
#define NH 8
#define HD 128
#define NFF 512
#define NE 8
#define NT 65536       /* B*S*H tokens */
#define NBS 8192       /* B*S rows */
#define MU_F 0.7f
#define LN_EPS_F 1e-5f

typedef __attribute__((ext_vector_type(4))) float f32x4;
typedef __attribute__((ext_vector_type(2))) double f64x2;
typedef __attribute__((ext_vector_type(8))) _Float16 f16x8;
typedef __attribute__((ext_vector_type(4))) _Float16 f16x4;
typedef __attribute__((ext_vector_type(2))) _Float16 f16x2;

__device__ __forceinline__ void gload_lds16(const void* g, void* l) {
  __builtin_amdgcn_global_load_lds(
      (const __attribute__((address_space(1))) unsigned int*)g,
      (__attribute__((address_space(3))) unsigned int*)l, 16, 0, 0);
}

// batched transpose + convert: in [batch][R][C] f32 -> out [batch][C][R] f16
__global__ void tr_cvt_kernel(const float* __restrict__ in, _Float16* __restrict__ out, int R, int C) {
  __shared__ float tile[32][33];
  int b = blockIdx.z;
  const float* inp = in + (size_t)b * R * C;
  _Float16* outp = out + (size_t)b * R * C;
  int c = blockIdx.x * 32 + threadIdx.x;
  int r0 = blockIdx.y * 32;
  #pragma unroll
  for (int i = 0; i < 4; i++) {
    int r = r0 + threadIdx.y + i * 8;
    tile[threadIdx.y + i * 8][threadIdx.x] = inp[(size_t)r * C + c];
  }
  __syncthreads();
  int rr = r0 + threadIdx.x;
  #pragma unroll
  for (int i = 0; i < 4; i++) {
    int cc = blockIdx.x * 32 + threadIdx.y + i * 8;
    outp[(size_t)cc * R + rr] = (_Float16)tile[threadIdx.x][threadIdx.y + i * 8];
  }
}

// one thread per G[d][o] scalar (65536 threads = 256 blocks, full GPU).
// Writes in Gx2 [kp][o] f64x2 layout (gate v6's staging layout).
// Also zeroes cnt (folds the old zero_cnt launch).
__global__ void build_G_kernel(const float* __restrict__ split_W, const float* __restrict__ split_b,
                               const float* __restrict__ gate_W, const float* __restrict__ gate_b,
                               double* __restrict__ G, double* __restrict__ gbias,
                               int* __restrict__ cnt) {
  int idx = blockIdx.x * 256 + threadIdx.x;   // = d*64 + o
  if (blockIdx.x == 0 && threadIdx.x < 256) { cnt[threadIdx.x] = 0; cnt[threadIdx.x + 256] = 0; }
  int d = idx >> 6, o = idx & 63, h = o >> 3, e = o & 7;
  double acc = 0.0;
  const float* r0 = split_W + (size_t)d * ND + h * 128;
  #pragma unroll 4
  for (int j = 0; j < 128; j++)
    acc += (double)r0[j] * (double)gate_W[j * 8 + e];
  G[((size_t)(d >> 1) * 64 + o) * 2 + (d & 1)] = acc;
  if (idx < 64) {
    double bacc = 0.0;
    for (int j = 0; j < 128; j++)
      bacc += (double)split_b[h * 128 + j] * (double)gate_W[j * 8 + e];
    gbias[idx] = bacc + (double)gate_b[e];
  }
}

// fp64 logits = x @ G + gbias, top-2 per (row,h), softmax, per-expert lists.
// v6 (REVERTED from failed fp64-MFMA v8; layout unverified): G chunk async-staged
// to LDS via global_load_lds (zero VGPR cost). Gx2 global layout == LDS layout ->
// linear 32KB copy; compute read Gs[kp*64+lane] is 16B/lane contiguous =
// conflict-free. Fused x->fp16 + hierarchical atomics.
__global__ __launch_bounds__(256) void gate_kernel(const float* __restrict__ x,
    const f64x2* __restrict__ Gx2, const double* __restrict__ gbias,
    _Float16* __restrict__ x_h,
    float* __restrict__ tkw, int* __restrict__ lists, int* __restrict__ cnt) {
  __shared__ f64x2 Gs[32 * 64];      // 32 KB, [kp][col] current chunk
  __shared__ double xsd[16][66];     // 8.25 KB
  __shared__ double lg[16 * 64];     // 8 KB
  __shared__ int lcnt[8];
  __shared__ int lbase[8];
  int tid = threadIdx.x, lane = tid & 63, w = tid >> 6;
  int bs0 = blockIdx.x * 16;
  double acc[4];
  #pragma unroll
  for (int r = 0; r < 4; r++) acc[r] = 0.0;
  int xrow = tid >> 4, xc4 = tid & 15;
  const double* xr = &xsd[0][0] + (w * 4) * 66;
  if (tid < 8) lcnt[tid] = 0;

  for (int ch = 0; ch < 16; ch++) {
    __syncthreads();           // previous chunk's reads complete before overwrite
    // stage x chunk (16 rows x 64 k) as double + fused fp16 convert
    float4 xv4 = *(const float4*)(x + (size_t)(bs0 + xrow) * ND + ch * 64 + xc4 * 4);
    f64x2 xa = { (double)xv4.x, (double)xv4.y };
    f64x2 xb = { (double)xv4.z, (double)xv4.w };
    *(f64x2*)&xsd[xrow][xc4 * 4]     = xa;
    *(f64x2*)&xsd[xrow][xc4 * 4 + 2] = xb;
    f16x4 xh = { (_Float16)xv4.x, (_Float16)xv4.y, (_Float16)xv4.z, (_Float16)xv4.w };
    *(f16x4*)(x_h + (size_t)(bs0 + xrow) * ND + ch * 64 + xc4 * 4) = xh;
    // async-stage G chunk: linear 32KB copy, no VGPR round-trip
    #pragma unroll
    for (int j = 0; j < 8; j++) {
      int n = j * 256 + tid;           // 0..2047 16B granules
      gload_lds16(Gx2 + (size_t)ch * 2048 + n, Gs + n);
    }
    __syncthreads();           // compiler drains vmcnt: G + x ready
    #pragma unroll 4
    for (int kp = 0; kp < 32; kp++) {
      f64x2 g = Gs[kp * 64 + lane];        // contiguous 16B/lane: conflict-free
      #pragma unroll
      for (int r = 0; r < 4; r++) {
        f64x2 xv = *(const f64x2*)(xr + r * 66 + kp * 2);   // LDS broadcast
        acc[r] += xv.x * g.x;
        acc[r] += xv.y * g.y;
      }
    }
  }
  double gb = gbias[lane];
  #pragma unroll
  for (int r = 0; r < 4; r++)
    lg[(w * 4 + r) * 64 + lane] = acc[r] + gb;
  __syncthreads();

  int i1 = 0, i2 = 0, token = 0, p1 = 0, p2 = 0;
  if (tid < 128) {
    int row = tid >> 3, h = tid & 7;
    const double* L = lg + row * 64 + h * 8;
    double v1 = L[0];
    #pragma unroll
    for (int e2 = 1; e2 < 8; e2++) if (L[e2] > v1) { v1 = L[e2]; i1 = e2; }
    i2 = -1; double v2 = -1e300;
    #pragma unroll
    for (int e2 = 0; e2 < 8; e2++) if (e2 != i1 && L[e2] > v2) { v2 = L[e2]; i2 = e2; }
    float ex = expf((float)(v2 - v1));        // <= 1
    float den = 1.f + ex;
    float g1 = 1.f / den, g2 = ex / den;
    token = (bs0 + row) * 8 + h;
    tkw[token * 2]     = g1;
    tkw[token * 2 + 1] = g2;
    p1 = atomicAdd(&lcnt[i1], 1);             // LDS atomics: cheap
    p2 = atomicAdd(&lcnt[i2], 1);
  }
  __syncthreads();
  if (tid < 8) lbase[tid] = atomicAdd(cnt + tid * 64, lcnt[tid]);   // 8 global atomics/block
  __syncthreads();
  if (tid < 128) {
    lists[(size_t)i1 * NT + lbase[i1] + p1] = token * 2;
    lists[(size_t)i2 * NT + lbase[i2] + p2] = token * 2 + 1;
  }
}

// C[M][N] = A[M][K] @ Bt[N][K]^T + bias; fp16 inputs, fp32 acc.
// 128x128 tile, BK=32, 4 waves (2x2 of 64x64), global_load_lds width 16.
// XCD-chunked bijective block swizzle (T1): XCD l&7 owns 8 contiguous
// A-row-panels (2MB) -> A+B L2-resident per XCD.
__global__ __launch_bounds__(256) void gemm_f16_kernel(
    const _Float16* __restrict__ A, const _Float16* __restrict__ Bt,
    const float* __restrict__ bias, float* __restrict__ Cf, _Float16* __restrict__ Ch,
    int M, int N, int Kd) {
  __shared__ _Float16 As[128 * 32];
  __shared__ _Float16 Bs[128 * 32];
  int tid = threadIdx.x, lane = tid & 63, w = tid >> 6;
  int wr = w >> 1, wc = w & 1;
  int lid = blockIdx.y * 8 + blockIdx.x;        // dispatch order (x fastest)
  int xcd = lid & 7, sub = (lid >> 3) & 7, grp = lid >> 6;
  int m0 = (xcd * 8 + sub) * 128;               // contiguous A-panels per XCD
  int n0 = grp * 128;
  f32x4 acc[4][4];
  #pragma unroll
  for (int i = 0; i < 4; i++)
    #pragma unroll
    for (int j = 0; j < 4; j++) acc[i][j] = (f32x4){0.f, 0.f, 0.f, 0.f};
  int srow = lane >> 2, scol = (lane & 3) * 8;
  int fr = lane & 15, ko = (lane >> 4) * 8;
  const _Float16* Ag = A + (size_t)(m0 + srow) * Kd + scol;
  const _Float16* Bg = Bt + (size_t)(n0 + srow) * Kd + scol;

  for (int k0 = 0; k0 < Kd; k0 += 32) {
    #pragma unroll
    for (int j = 0; j < 2; j++) {
      int rb = (w * 2 + j) * 16;
      gload_lds16(Ag + (size_t)rb * Kd + k0, As + rb * 32);
      gload_lds16(Bg + (size_t)rb * Kd + k0, Bs + rb * 32);
    }
    __syncthreads();
    f16x8 af[4], bq[4];
    #pragma unroll
    for (int mi = 0; mi < 4; mi++) af[mi] = *(const f16x8*)(As + (wr * 64 + mi * 16 + fr) * 32 + ko);
    #pragma unroll
    for (int ni = 0; ni < 4; ni++) bq[ni] = *(const f16x8*)(Bs + (wc * 64 + ni * 16 + fr) * 32 + ko);
    __syncthreads();
    #pragma unroll
    for (int mi = 0; mi < 4; mi++)
      #pragma unroll
      for (int ni = 0; ni < 4; ni++)
        acc[mi][ni] = __builtin_amdgcn_mfma_f32_16x16x32_f16(af[mi], bq[ni], acc[mi][ni], 0, 0, 0);
  }
  int rbase = m0 + wr * 64 + ((lane >> 4) << 2);
  int cbase = n0 + wc * 64 + (lane & 15);
  #pragma unroll
  for (int mi = 0; mi < 4; mi++)
    #pragma unroll
    for (int ni = 0; ni < 4; ni++) {
      int cc = cbase + ni * 16;
      float bv = bias ? bias[cc] : 0.f;
      #pragma unroll
      for (int r = 0; r < 4; r++) {
        int rr = rbase + mi * 16 + r;
        float v = acc[mi][ni][r] + bv;
        if (Cf) Cf[(size_t)rr * N + cc] = v;
        if (Ch) Ch[(size_t)rr * N + cc] = (_Float16)v;
      }
    }
}

// Grouped expert kernel v9 = v7 + swapped-operand phase A (acc1 = mfma(bq, af)
// computes h^T: reg-quad = 4 consecutive ff for one token -> single b64 h-write).
// 3-ring counted-vmcnt staging; phase B/epilogue as v7.
__global__ __launch_bounds__(512, 2) void expert_kernel(
    const _Float16* __restrict__ t_h, const _Float16* __restrict__ W1t, const _Float16* __restrict__ W2t,
    const float* __restrict__ b1, const float* __restrict__ b2,
    const int* __restrict__ cnt, const int* __restrict__ lists, const float* __restrict__ tkw,
    _Float16* __restrict__ slots) {
  int e = blockIdx.x & 7;              // consecutive blocks -> different XCDs
  int m0 = (blockIdx.x >> 3) * 128;
  int count = cnt[e * 64];
  if (m0 >= count) return;
  __shared__ _Float16 ring[3][64 * 128];  // 3 x 16 KB staging ring
  __shared__ _Float16 h_s[128 * 64];      // 16 KB [tok128][ff64] 128B rows
  __shared__ float b1s[NFF];              // 2 KB
  __shared__ float b2s[HD];               // 512 B
  __shared__ int alist[128];
  __shared__ float aw[128];
  int tid = threadIdx.x, lane = tid & 63, w = tid >> 6;
  int wr = w >> 1, wc = w & 1;         // 4 row-quarters (32) x 2 col-halves (64)
  int fr = lane & 15, g = lane >> 4;

  if (tid < 128) {
    int idx = m0 + tid;
    int a = (idx < count) ? lists[(size_t)e * NT + idx] : -1;
    alist[tid] = a;
    aw[tid] = (a >= 0) ? tkw[a] : 0.f;
  }
  b1s[tid] = b1[e * NFF + tid];
  if (tid < 128) b2s[tid] = b2[e * HD + tid];
  __syncthreads();

  auto stage = [&](int p) {
    if (p >= 16) return;
    int ch = p >> 1;
    _Float16* dst = &ring[p % 3][0];
    if ((p & 1) == 0) {
      #pragma unroll
      for (int j = 0; j < 2; j++) {
        int n = j * 512 + tid;           // 16 granules per 256B row
        int r = n >> 4, gg = n & 15;
        int sg = gg ^ ((r >> 1) & 7);
        gload_lds16(W1t + (size_t)e * (NFF * HD) + (size_t)(ch * 64 + r) * HD + sg * 8, dst + n * 8);
      }
    } else {
      #pragma unroll
      for (int j = 0; j < 2; j++) {
        int n = j * 512 + tid;           // 8 granules per 128B row
        int r = n >> 3, gg = n & 7;
        int sg = gg ^ ((r >> 1) & 7);
        gload_lds16(W2t + (size_t)e * (HD * NFF) + (size_t)r * NFF + ch * 64 + sg * 8, dst + n * 8);
      }
    }
  };

  // gather this wave's 32 token rows into registers (held across all phases)
  f16x8 af[2][4];
  #pragma unroll
  for (int mi = 0; mi < 2; mi++) {
    int rloc = wr * 32 + mi * 16 + fr;
    int a = alist[rloc];
    const _Float16* tb = t_h + (size_t)(a >> 1) * HD;
    #pragma unroll
    for (int ks = 0; ks < 4; ks++) {
      f16x8 v = {0, 0, 0, 0, 0, 0, 0, 0};
      if (a >= 0) v = *(const f16x8*)(tb + ks * 32 + g * 8);
      af[mi][ks] = v;
    }
  }
  asm volatile("s_waitcnt vmcnt(0)" ::: "memory");   // drain gather: loop vmcnt is stage-only
  stage(0); stage(1);
  asm volatile("s_waitcnt vmcnt(2) lgkmcnt(0)\n\ts_barrier" ::: "memory");  // stage(0) landed

  f32x4 acc2[2][4];
  #pragma unroll
  for (int i = 0; i < 2; i++)
    #pragma unroll
    for (int j = 0; j < 4; j++) acc2[i][j] = (f32x4){0.f, 0.f, 0.f, 0.f};

  #pragma unroll
  for (int p = 0; p < 16; p++) {
    stage(p + 2);
    int ch = p >> 1;
    const char* WB = (const char*)&ring[p % 3][0];
    if ((p & 1) == 0) {
      // ---- A (swapped): acc1 = W1^T . t^T = h^T; reg-quad = 4 consecutive ff ----
      float b1r[2][4];
      #pragma unroll
      for (int ni = 0; ni < 2; ni++)
        #pragma unroll
        for (int r = 0; r < 4; r++)
          b1r[ni][r] = b1s[ch * 64 + wc * 32 + ni * 16 + g * 4 + r];
      f32x4 acc1[2][2];    // [mi tok-block][ni ff-block]
      #pragma unroll
      for (int i = 0; i < 2; i++)
        #pragma unroll
        for (int j = 0; j < 2; j++) acc1[i][j] = (f32x4){0.f, 0.f, 0.f, 0.f};
      #pragma unroll
      for (int ks = 0; ks < 4; ks++) {
        f16x8 bq[2];
        #pragma unroll
        for (int ni = 0; ni < 2; ni++) {
          int rw = wc * 32 + ni * 16 + fr;       // ff row of chunk (0..63)
          int byte = rw * 256 + ((ks * 64 + g * 16) ^ (((rw >> 1) & 7) << 4));
          bq[ni] = *(const f16x8*)(WB + byte);
        }
        #pragma unroll
        for (int mi = 0; mi < 2; mi++)
          #pragma unroll
          for (int ni = 0; ni < 2; ni++)
            acc1[mi][ni] = __builtin_amdgcn_mfma_f32_16x16x32_f16(bq[ni], af[mi][ks], acc1[mi][ni], 0, 0, 0);
      }
      // relu + bias -> pack 4 consecutive ff -> single b64 write per (mi,ni)
      #pragma unroll
      for (int mi = 0; mi < 2; mi++)
        #pragma unroll
        for (int ni = 0; ni < 2; ni++) {
          f16x4 hv;
          #pragma unroll
          for (int r = 0; r < 4; r++)
            hv[r] = (_Float16)fmaxf(acc1[mi][ni][r] + b1r[ni][r], 0.f);
          int tok = wr * 32 + mi * 16 + fr;
          int foff = wc * 64 + ni * 32 + g * 8;       // ff*2 bytes
          int byte = tok * 128 + (foff ^ (((tok >> 1) & 7) << 4));
          *(f16x4*)((char*)h_s + byte) = hv;
        }
    } else {
      // ---- B: acc2 += h(:, ch) @ W2chunk ----
      #pragma unroll
      for (int ks = 0; ks < 2; ks++) {
        f16x8 ah[2], bq[4];
        #pragma unroll
        for (int mi = 0; mi < 2; mi++) {
          int row = wr * 32 + mi * 16 + fr;
          int byte = row * 128 + ((ks * 64 + g * 16) ^ (((row >> 1) & 7) << 4));
          ah[mi] = *(const f16x8*)((const char*)h_s + byte);
        }
        #pragma unroll
        for (int ni = 0; ni < 4; ni++) {
          int rw = wc * 64 + ni * 16 + fr;       // d row (0..127)
          int byte = rw * 128 + ((ks * 64 + g * 16) ^ (((rw >> 1) & 7) << 4));
          bq[ni] = *(const f16x8*)((const char*)&ring[p % 3][0] + byte);
        }
        #pragma unroll
        for (int mi = 0; mi < 2; mi++)
          #pragma unroll
          for (int ni = 0; ni < 4; ni++)
            acc2[mi][ni] = __builtin_amdgcn_mfma_f32_16x16x32_f16(ah[mi], bq[ni], acc2[mi][ni], 0, 0, 0);
      }
    }
    if (p == 14) {
      asm volatile("s_waitcnt vmcnt(0) lgkmcnt(0)\n\ts_barrier" ::: "memory");
    } else if (p < 14) {
      asm volatile("s_waitcnt vmcnt(2) lgkmcnt(0)\n\ts_barrier" ::: "memory");
    }
  }
  // epilogue: gate-scale + fp16 scatter to slots
  #pragma unroll
  for (int mi = 0; mi < 2; mi++)
    #pragma unroll
    for (int ni = 0; ni < 4; ni++) {
      int ncol = wc * 64 + ni * 16 + fr;
      float bv = b2s[ncol];
      #pragma unroll
      for (int r = 0; r < 4; r++) {
        int m = wr * 32 + mi * 16 + g * 4 + r;
        int a = alist[m];
        if (a >= 0)
          slots[(size_t)a * HD + ncol] = (_Float16)(aw[m] * (acc2[mi][ni][r] + bv));
      }
    }
}

// combine slots -> momentum update -> residual -> LayerNorm
__global__ __launch_bounds__(256) void combine_ln_kernel(
    const _Float16* __restrict__ slots, const float* __restrict__ momentum,
    const _Float16* __restrict__ t_h, const float* __restrict__ ln_g, const float* __restrict__ ln_b,
    float* __restrict__ nm_out, _Float16* __restrict__ out_h) {
  int w = threadIdx.x >> 6, lane = threadIdx.x & 63;
  int tok = blockIdx.x * 4 + w;
  int d0 = lane * 2;
  f16x2 s0 = *(const f16x2*)(slots + (size_t)tok * 256 + d0);
  f16x2 s1 = *(const f16x2*)(slots + (size_t)tok * 256 + 128 + d0);
  float2 mo = *(const float2*)(momentum + (size_t)tok * HD + d0);
  f16x2 tv = *(const f16x2*)(t_h + (size_t)tok * HD + d0);
  float nm0 = -((float)s0.x + (float)s1.x) + MU_F * mo.x;
  float nm1 = -((float)s0.y + (float)s1.y) + MU_F * mo.y;
  float2 nm2; nm2.x = nm0; nm2.y = nm1;
  *(float2*)(nm_out + (size_t)tok * HD + d0) = nm2;
  float r0 = (float)tv.x + nm0;
  float r1 = (float)tv.y + nm1;
  float s = r0 + r1, sq = r0 * r0 + r1 * r1;
  #pragma unroll
  for (int m = 1; m < 64; m <<= 1) { s += __shfl_xor(s, m, 64); sq += __shfl_xor(sq, m, 64); }
  float mean = s * (1.f / 128.f);
  float var = sq * (1.f / 128.f) - mean * mean;
  float is = rsqrtf(var + LN_EPS_F);
  float y0 = (r0 - mean) * is * ln_g[d0] + ln_b[d0];
  float y1 = (r1 - mean) * is * ln_g[d0 + 1] + ln_b[d0 + 1];
  f16x2 yo = { (_Float16)y0, (_Float16)y1 };
  *(f16x2*)(out_h + (size_t)tok * HD + d0) = yo;
}

extern "C" void kernel_launch(void* const* d_in, const int* in_sizes, int n_in,
                              void* d_out, int out_size, void* d_ws, size_t ws_size,
                              hipStream_t stream) {
  const float* x        = (const float*)d_in[0];
  const float* momentum = (const float*)d_in[1];
  const float* split_W  = (const float*)d_in[2];
  const float* split_b  = (const float*)d_in[3];
  const float* gate_W   = (const float*)d_in[4];
  const float* gate_b   = (const float*)d_in[5];
  const float* W1       = (const float*)d_in[6];
  const float* b1       = (const float*)d_in[7];
  const float* W2       = (const float*)d_in[8];
  const float* b2       = (const float*)d_in[9];
  const float* ln_g     = (const float*)d_in[10];
  const float* ln_b     = (const float*)d_in[11];
  const float* merge_W  = (const float*)d_in[12];
  const float* merge_b  = (const float*)d_in[13];
  float* final_out = (float*)d_out;
  float* nm_out    = final_out + (size_t)NBS * ND;

  char* ws = (char*)d_ws;
  size_t off = 0;
  auto alloc = [&](size_t bytes) { void* p = ws + off; off = (off + bytes + 255) & ~(size_t)255; return p; };
  _Float16* x_h   = (_Float16*)alloc((size_t)NBS * ND * 2);
  _Float16* t_h   = (_Float16*)alloc((size_t)NT * HD * 2);
  _Float16* out_h = (_Float16*)alloc((size_t)NT * HD * 2);
  _Float16* sWt   = (_Float16*)alloc((size_t)ND * ND * 2);
  _Float16* mWt   = (_Float16*)alloc((size_t)ND * ND * 2);
  _Float16* W1t   = (_Float16*)alloc((size_t)NE * HD * NFF * 2);
  _Float16* W2t   = (_Float16*)alloc((size_t)NE * HD * NFF * 2);
  f64x2*    Gx2   = (f64x2*)alloc((size_t)512 * 64 * 16);
  double*   gbias = (double*)alloc(64 * 8);
  float*    tkw   = (float*)alloc((size_t)NT * 2 * 4);
  int*      lists = (int*)alloc((size_t)NE * NT * 4);
  int*      cnt   = (int*)alloc(512 * 4);
  _Float16* slots = (_Float16*)alloc((size_t)NT * 2 * HD * 2);
  (void)in_sizes; (void)n_in; (void)out_size; (void)ws_size;

  tr_cvt_kernel<<<dim3(32, 32, 1), dim3(32, 8), 0, stream>>>(split_W, sWt, ND, ND);
  tr_cvt_kernel<<<dim3(32, 32, 1), dim3(32, 8), 0, stream>>>(merge_W, mWt, ND, ND);
  tr_cvt_kernel<<<dim3(16, 4, 8), dim3(32, 8), 0, stream>>>(W1, W1t, HD, NFF);
  tr_cvt_kernel<<<dim3(4, 16, 8), dim3(32, 8), 0, stream>>>(W2, W2t, NFF, HD);
  build_G_kernel<<<256, 256, 0, stream>>>(split_W, split_b, gate_W, gate_b, (double*)Gx2, gbias, cnt);
  // gate also produces x_h (fused convert), so it runs before the split GEMM
  gate_kernel<<<512, 256, 0, stream>>>(x, Gx2, gbias, x_h, tkw, lists, cnt);
  // t = x @ split_W + split_b   (fp16 out for downstream MFMA)
  gemm_f16_kernel<<<dim3(8, 64), 256, 0, stream>>>(x_h, sWt, split_b, nullptr, t_h, NBS, ND, ND);
  expert_kernel<<<NE * 512, 512, 0, stream>>>(t_h, W1t, W2t, b1, b2, cnt, lists, tkw, slots);
  combine_ln_kernel<<<NT / 4, 256, 0, stream>>>(slots, momentum, t_h, ln_g, ln_b, nm_out, out_h);
  // final = out @ merge_W + merge_b
  gemm_f16_kernel<<<dim3(8, 64), 256, 0, stream>>>(out_h, mWt, merge_b, final_out, nullptr, NBS, ND, ND);
}